// Round 1
// baseline (2869.009 us; speedup 1.0000x reference)
//
#include <hip/hip_runtime.h>
#include <cstdint>
#include <cstddef>

#define DD 64

// ---------- float4 helpers ----------
__device__ __forceinline__ float4 f4_0() { return make_float4(0.f, 0.f, 0.f, 0.f); }

// ---------- row GEMM: acc[d] += row[k] * W[k*64+d], k=0..63 ----------
// W is wave-uniform (kernel arg) -> compiler emits s_load; row is per-lane.
__device__ __forceinline__ void row_gemm64(const float* __restrict__ row,
                                           const float* __restrict__ W,
                                           float acc[DD]) {
  for (int k4 = 0; k4 < DD; k4 += 4) {
    const float4 rv = *reinterpret_cast<const float4*>(row + k4);
    const float rvals[4] = {rv.x, rv.y, rv.z, rv.w};
#pragma unroll
    for (int kk = 0; kk < 4; ++kk) {
      const float v = rvals[kk];
      const float* wr = W + (k4 + kk) * DD;
#pragma unroll
      for (int d = 0; d < DD; ++d) acc[d] = fmaf(v, wr[d], acc[d]);
    }
  }
}

__device__ __forceinline__ void init_bias64(const float* __restrict__ b, float acc[DD]) {
#pragma unroll
  for (int d = 0; d < DD; ++d) acc[d] = b[d];
}

// ---------- CSR build ----------
__global__ __launch_bounds__(256) void k_hist(const int* __restrict__ dst,
                                              int* __restrict__ cnt, int E) {
  int j = blockIdx.x * 256 + threadIdx.x;
  if (j < E) atomicAdd(&cnt[dst[j]], 1);
}

__global__ __launch_bounds__(1024) void k_scan(const int* __restrict__ cnt,
                                               int* __restrict__ row_ptr,
                                               int* __restrict__ nxt, int N, int E) {
  __shared__ int tile[1024];
  __shared__ int carry;
  const int tid = threadIdx.x;
  if (tid == 0) carry = 0;
  __syncthreads();
  const int nt = (N + 1023) / 1024;
  for (int b = 0; b < nt; ++b) {
    int i = b * 1024 + tid;
    int v = (i < N) ? cnt[i] : 0;
    tile[tid] = v;
    __syncthreads();
    for (int off = 1; off < 1024; off <<= 1) {
      int t = (tid >= off) ? tile[tid - off] : 0;
      __syncthreads();
      tile[tid] += t;
      __syncthreads();
    }
    int excl = carry + tile[tid] - v;
    if (i < N) { row_ptr[i] = excl; nxt[i] = excl; }
    __syncthreads();
    if (tid == 0) carry += tile[1023];
    __syncthreads();
  }
  if (tid == 0) row_ptr[N] = E;
}

__global__ __launch_bounds__(256) void k_scatter(const int* __restrict__ dst,
                                                 int* __restrict__ nxt,
                                                 int* __restrict__ order, int E) {
  int j = blockIdx.x * 256 + threadIdx.x;
  if (j >= E) return;
  int pos = atomicAdd(&nxt[dst[j]], 1);
  order[pos] = j;
}

// ---------- conv1d (4->64, K=16, L=128, valid) + global maxpool ----------
__global__ __launch_bounds__(256) void k_conv(const float* __restrict__ reads,
                                              const float* __restrict__ w,
                                              const float* __restrict__ bias,
                                              float* __restrict__ h, int N) {
  __shared__ float r[4][4][144];  // 4 nodes x 4 ch x (128 + pad)
  const int tid = threadIdx.x;
  const int nb = blockIdx.x * 4;
  {  // zero the pad region (exactly 256 entries)
    int node = tid >> 6, c = (tid >> 4) & 3, pp = tid & 15;
    r[node][c][128 + pp] = 0.f;
  }
  for (int f = tid; f < 512; f += 256) {  // 512 float4 loads for 4 nodes
    int node = f >> 7;
    int rem = f & 127;
    int gn = nb + node;
    float4 v = f4_0();
    if (gn < N) v = *reinterpret_cast<const float4*>(reads + (size_t)gn * 512 + rem * 4);
    int c = rem >> 5, pp = (rem & 31) << 2;
    *reinterpret_cast<float4*>(&r[node][c][pp]) = v;
  }
  __syncthreads();
  const int node = tid >> 6, d = tid & 63;
  const int gn = nb + node;
  if (gn >= N) return;
  float wreg[64];
#pragma unroll
  for (int q = 0; q < 16; ++q) {
    float4 v = *reinterpret_cast<const float4*>(w + d * 64 + q * 4);
    wreg[q * 4] = v.x; wreg[q * 4 + 1] = v.y; wreg[q * 4 + 2] = v.z; wreg[q * 4 + 3] = v.w;
  }
  const float b = bias[d];
  float best = -3.0e38f;
  for (int t0 = 0; t0 < 113; t0 += 4) {
    float s0 = b, s1 = b, s2 = b, s3 = b;
#pragma unroll
    for (int c = 0; c < 4; ++c) {
      float win[20];
#pragma unroll
      for (int q = 0; q < 5; ++q) {
        float4 v = *reinterpret_cast<const float4*>(&r[node][c][t0 + q * 4]);
        win[q * 4] = v.x; win[q * 4 + 1] = v.y; win[q * 4 + 2] = v.z; win[q * 4 + 3] = v.w;
      }
#pragma unroll
      for (int k = 0; k < 16; ++k) {
        float wv = wreg[c * 16 + k];
        s0 = fmaf(win[k], wv, s0);
        s1 = fmaf(win[k + 1], wv, s1);
        s2 = fmaf(win[k + 2], wv, s2);
        s3 = fmaf(win[k + 3], wv, s3);
      }
    }
    best = fmaxf(best, s0);
    if (t0 + 1 < 113) best = fmaxf(best, s1);
    if (t0 + 2 < 113) best = fmaxf(best, s2);
    if (t0 + 3 < 113) best = fmaxf(best, s3);
  }
  h[(size_t)gn * 64 + d] = best;
}

// ---------- edge encoder: e = [sim,len] @ We + be ----------
__global__ __launch_bounds__(256) void k_edge_enc(const float* __restrict__ sim,
                                                  const float* __restrict__ len,
                                                  const float* __restrict__ We,
                                                  const float* __restrict__ be,
                                                  float* __restrict__ e, int E) {
  int idx = blockIdx.x * 256 + threadIdx.x;
  if (idx >= E * 16) return;
  int j = idx >> 4, dc = (idx & 15) << 2;
  float s = sim[j], L = len[j];
  float4 w0 = *reinterpret_cast<const float4*>(We + dc);
  float4 w1 = *reinterpret_cast<const float4*>(We + 64 + dc);
  float4 b  = *reinterpret_cast<const float4*>(be + dc);
  float4 o;
  o.x = fmaf(s, w0.x, fmaf(L, w1.x, b.x));
  o.y = fmaf(s, w0.y, fmaf(L, w1.y, b.y));
  o.z = fmaf(s, w0.z, fmaf(L, w1.z, b.z));
  o.w = fmaf(s, w0.w, fmaf(L, w1.w, b.w));
  *reinterpret_cast<float4*>(e + (size_t)j * 64 + dc) = o;
}

// ---------- node GEMMs: X = h @ W + b for 3 matrices (blockIdx.y picks) ----------
__global__ __launch_bounds__(256) void k_node_gemm(const float* __restrict__ h,
                                                   const float* __restrict__ Wa,
                                                   const float* __restrict__ Wb,
                                                   const float* __restrict__ Wc,
                                                   const float* __restrict__ ba,
                                                   const float* __restrict__ bb,
                                                   const float* __restrict__ bc,
                                                   float* __restrict__ Xa,
                                                   float* __restrict__ Xb,
                                                   float* __restrict__ Xc, int N) {
  const float* W; const float* bi; float* X;
  if (blockIdx.y == 0)      { W = Wa; bi = ba; X = Xa; }
  else if (blockIdx.y == 1) { W = Wb; bi = bb; X = Xb; }
  else                      { W = Wc; bi = bc; X = Xc; }
  int n = blockIdx.x * 256 + threadIdx.x;
  if (n >= N) return;
  float acc[DD];
  init_bias64(bi, acc);
  row_gemm64(h + (size_t)n * 64, W, acc);
#pragma unroll
  for (int dc = 0; dc < DD; dc += 4) {
    float4 v = make_float4(acc[dc], acc[dc + 1], acc[dc + 2], acc[dc + 3]);
    *reinterpret_cast<float4*>(X + (size_t)n * 64 + dc) = v;
  }
}

// ---------- edge compute: ehat = XA1[src] + XA2[dst] + e@A3 + bA3 ----------
__global__ __launch_bounds__(256) void k_edge_compute(const float* __restrict__ e,
                                                      const int* __restrict__ src,
                                                      const int* __restrict__ dst,
                                                      const float* __restrict__ XA1,
                                                      const float* __restrict__ XA2,
                                                      const float* __restrict__ A3,
                                                      const float* __restrict__ bA3,
                                                      float* __restrict__ ehat, int E) {
  int j = blockIdx.x * 256 + threadIdx.x;
  if (j >= E) return;
  float acc[DD];
  init_bias64(bA3, acc);
  row_gemm64(e + (size_t)j * 64, A3, acc);
  int s = src[j], t = dst[j];
#pragma unroll
  for (int dc = 0; dc < DD; dc += 4) {
    float4 a = *reinterpret_cast<const float4*>(XA1 + (size_t)s * 64 + dc);
    float4 b = *reinterpret_cast<const float4*>(XA2 + (size_t)t * 64 + dc);
    float4 o = make_float4(acc[dc] + a.x + b.x, acc[dc + 1] + a.y + b.y,
                           acc[dc + 2] + a.z + b.z, acc[dc + 3] + a.w + b.w);
    *reinterpret_cast<float4*>(ehat + (size_t)j * 64 + dc) = o;
  }
}

// ---------- aggregation via CSR: num = sum sigma*XV[src], den = sum sigma ----------
__global__ __launch_bounds__(256) void k_aggregate(const int* __restrict__ row_ptr,
                                                   const int* __restrict__ order,
                                                   const int* __restrict__ src,
                                                   const float* __restrict__ ehat,
                                                   const float* __restrict__ XV,
                                                   float* __restrict__ num,
                                                   float* __restrict__ den, int N) {
  int idx = blockIdx.x * 256 + threadIdx.x;
  if (idx >= N * 16) return;
  int n = idx >> 4, dc = (idx & 15) << 2;
  int beg = row_ptr[n], end = row_ptr[n + 1];
  float4 nm = f4_0(), dn = f4_0();
  for (int i = beg; i < end; ++i) {
    int eid = order[i];
    int sj = src[eid];
    float4 eh = *reinterpret_cast<const float4*>(ehat + (size_t)eid * 64 + dc);
    float4 vv = *reinterpret_cast<const float4*>(XV + (size_t)sj * 64 + dc);
    float4 sg;
    sg.x = 1.f / (1.f + __expf(-eh.x));
    sg.y = 1.f / (1.f + __expf(-eh.y));
    sg.z = 1.f / (1.f + __expf(-eh.z));
    sg.w = 1.f / (1.f + __expf(-eh.w));
    dn.x += sg.x; dn.y += sg.y; dn.z += sg.z; dn.w += sg.w;
    nm.x = fmaf(sg.x, vv.x, nm.x); nm.y = fmaf(sg.y, vv.y, nm.y);
    nm.z = fmaf(sg.z, vv.z, nm.z); nm.w = fmaf(sg.w, vv.w, nm.w);
  }
  *reinterpret_cast<float4*>(num + (size_t)n * 64 + dc) = nm;
  *reinterpret_cast<float4*>(den + (size_t)n * 64 + dc) = dn;
}

// ---------- h_hat = h @ U + bU + num/(den+eps) ----------
__global__ __launch_bounds__(256) void k_hhat(const float* __restrict__ h,
                                              const float* __restrict__ Uw,
                                              const float* __restrict__ bU,
                                              const float* __restrict__ num,
                                              const float* __restrict__ den,
                                              float* __restrict__ hhat, int N) {
  int n = blockIdx.x * 256 + threadIdx.x;
  if (n >= N) return;
  float acc[DD];
  init_bias64(bU, acc);
  row_gemm64(h + (size_t)n * 64, Uw, acc);
#pragma unroll
  for (int dc = 0; dc < DD; dc += 4) {
    float4 nm = *reinterpret_cast<const float4*>(num + (size_t)n * 64 + dc);
    float4 dn = *reinterpret_cast<const float4*>(den + (size_t)n * 64 + dc);
    float4 o = make_float4(acc[dc] + nm.x / (dn.x + 1e-6f),
                           acc[dc + 1] + nm.y / (dn.y + 1e-6f),
                           acc[dc + 2] + nm.z / (dn.z + 1e-6f),
                           acc[dc + 3] + nm.w / (dn.w + 1e-6f));
    *reinterpret_cast<float4*>(hhat + (size_t)n * 64 + dc) = o;
  }
}

// ---------- per-channel sum & sumsq over rows ----------
__global__ __launch_bounds__(256) void k_stats(const float* __restrict__ X, int R,
                                               float* __restrict__ sums) {
  __shared__ float red[2][16][64];
  int tid = threadIdx.x;
  int g = tid >> 4, dc = (tid & 15) << 2;
  float4 s = f4_0(), q = f4_0();
  for (int r = blockIdx.x * 16 + g; r < R; r += gridDim.x * 16) {
    float4 v = *reinterpret_cast<const float4*>(X + (size_t)r * 64 + dc);
    s.x += v.x; s.y += v.y; s.z += v.z; s.w += v.w;
    q.x = fmaf(v.x, v.x, q.x); q.y = fmaf(v.y, v.y, q.y);
    q.z = fmaf(v.z, v.z, q.z); q.w = fmaf(v.w, v.w, q.w);
  }
  *reinterpret_cast<float4*>(&red[0][g][dc]) = s;
  *reinterpret_cast<float4*>(&red[1][g][dc]) = q;
  __syncthreads();
  if (g == 0) {
    float4 ts = f4_0(), tq = f4_0();
#pragma unroll
    for (int gg = 0; gg < 16; ++gg) {
      float4 a = *reinterpret_cast<const float4*>(&red[0][gg][dc]);
      float4 b = *reinterpret_cast<const float4*>(&red[1][gg][dc]);
      ts.x += a.x; ts.y += a.y; ts.z += a.z; ts.w += a.w;
      tq.x += b.x; tq.y += b.y; tq.z += b.z; tq.w += b.w;
    }
    atomicAdd(&sums[dc], ts.x); atomicAdd(&sums[dc + 1], ts.y);
    atomicAdd(&sums[dc + 2], ts.z); atomicAdd(&sums[dc + 3], ts.w);
    atomicAdd(&sums[64 + dc], tq.x); atomicAdd(&sums[64 + dc + 1], tq.y);
    atomicAdd(&sums[64 + dc + 2], tq.z); atomicAdd(&sums[64 + dc + 3], tq.w);
  }
}

// ---------- fold BN stats into scale/shift ----------
__global__ void k_finalize(const float* __restrict__ sums, int E, int N,
                           const float* __restrict__ ge, const float* __restrict__ bbe,
                           const float* __restrict__ gh, const float* __restrict__ bbh,
                           float* __restrict__ coef) {
  int t = threadIdx.x;
  if (t < 64) {
    float mean = sums[t] / (float)E;
    float var = sums[64 + t] / (float)E - mean * mean;
    float sc = ge[t] * rsqrtf(var + 1e-5f);
    coef[t] = sc;
    coef[64 + t] = bbe[t] - mean * sc;
  } else if (t < 128) {
    int c = t - 64;
    float mean = sums[128 + c] / (float)N;
    float var = sums[192 + c] / (float)N - mean * mean;
    float sc = gh[c] * rsqrtf(var + 1e-5f);
    coef[128 + c] = sc;
    coef[192 + c] = bbh[c] - mean * sc;
  }
}

// ---------- X += relu(scale*Y + shift) ----------
__global__ __launch_bounds__(256) void k_update(float* __restrict__ X,
                                                const float* __restrict__ Y,
                                                const float* __restrict__ coef, int R) {
  int idx = blockIdx.x * 256 + threadIdx.x;
  if (idx >= R * 16) return;
  int r = idx >> 4, dc = (idx & 15) << 2;
  float4 sc = *reinterpret_cast<const float4*>(coef + dc);
  float4 sh = *reinterpret_cast<const float4*>(coef + 64 + dc);
  size_t off = (size_t)r * 64 + dc;
  float4 y = *reinterpret_cast<const float4*>(Y + off);
  float4 x = *reinterpret_cast<const float4*>(X + off);
  x.x += fmaxf(fmaf(sc.x, y.x, sh.x), 0.f);
  x.y += fmaxf(fmaf(sc.y, y.y, sh.y), 0.f);
  x.z += fmaxf(fmaf(sc.z, y.z, sh.z), 0.f);
  x.w += fmaxf(fmaf(sc.w, y.w, sh.w), 0.f);
  *reinterpret_cast<float4*>(X + off) = x;
}

// ---------- decoder: p = relu([h_s,h_d,e] @ W1 + b1) @ W2 + b2 ----------
__global__ __launch_bounds__(256) void k_decoder(const float* __restrict__ h,
                                                 const float* __restrict__ e,
                                                 const int* __restrict__ src,
                                                 const int* __restrict__ dst,
                                                 const float* __restrict__ W1,
                                                 const float* __restrict__ b1,
                                                 const float* __restrict__ W2,
                                                 const float* __restrict__ b2,
                                                 float* __restrict__ out, int E) {
  int j = blockIdx.x * 256 + threadIdx.x;
  if (j >= E) return;
  int s = src[j], t = dst[j];
  float acc[DD];
  init_bias64(b1, acc);
  row_gemm64(h + (size_t)s * 64, W1, acc);
  row_gemm64(h + (size_t)t * 64, W1 + 64 * 64, acc);
  row_gemm64(e + (size_t)j * 64, W1 + 128 * 64, acc);
  float p = b2[0];
#pragma unroll
  for (int d = 0; d < DD; ++d) p = fmaf(fmaxf(acc[d], 0.f), W2[d], p);
  out[j] = p;
}

extern "C" void kernel_launch(void* const* d_in, const int* in_sizes, int n_in,
                              void* d_out, int out_size, void* d_ws, size_t ws_size,
                              hipStream_t stream) {
  const float* reads  = (const float*)d_in[0];
  const int*   src    = (const int*)d_in[1];
  const int*   dst    = (const int*)d_in[2];
  const float* sim    = (const float*)d_in[3];
  const float* olen   = (const float*)d_in[4];
  const float* conv_w = (const float*)d_in[5];
  const float* conv_b = (const float*)d_in[6];
  const float* We     = (const float*)d_in[7];
  const float* be     = (const float*)d_in[8];
  const float* A1     = (const float*)d_in[9];
  const float* A2     = (const float*)d_in[10];
  const float* A3     = (const float*)d_in[11];
  const float* bA1    = (const float*)d_in[12];
  const float* bA2    = (const float*)d_in[13];
  const float* bA3    = (const float*)d_in[14];
  const float* U      = (const float*)d_in[15];
  const float* V      = (const float*)d_in[16];
  const float* bU     = (const float*)d_in[17];
  const float* bV     = (const float*)d_in[18];
  const float* bnhg   = (const float*)d_in[19];
  const float* bnhb   = (const float*)d_in[20];
  const float* bneg   = (const float*)d_in[21];
  const float* bneb   = (const float*)d_in[22];
  const float* W1     = (const float*)d_in[23];
  const float* b1     = (const float*)d_in[24];
  const float* W2     = (const float*)d_in[25];
  const float* b2     = (const float*)d_in[26];

  const int N = in_sizes[0] / 512;   // reads: [N,4,128]
  const int E = in_sizes[1];

  float* p = (float*)d_ws;
  float* h    = p; p += (size_t)N * 64;
  float* e    = p; p += (size_t)E * 64;
  float* ehat = p; p += (size_t)E * 64;
  float* XA1  = p; p += (size_t)N * 64;
  float* XA2  = p; p += (size_t)N * 64;
  float* XV   = p; p += (size_t)N * 64;
  float* hhat = p; p += (size_t)N * 64;
  float* numb = p; p += (size_t)N * 64;
  float* denb = p; p += (size_t)N * 64;
  float* sums = p; p += 256;
  float* coef = p; p += 256;
  int* ip = (int*)p;
  int* cnt     = ip; ip += N;
  int* row_ptr = ip; ip += N + 1;
  int* nxt     = ip; ip += N;
  int* order   = ip; ip += E;
  float* out = (float*)d_out;

  // CSR of dst (fixed input; rebuilt each launch for determinism rules)
  hipMemsetAsync(cnt, 0, sizeof(int) * N, stream);
  k_hist<<<(E + 255) / 256, 256, 0, stream>>>(dst, cnt, E);
  k_scan<<<1, 1024, 0, stream>>>(cnt, row_ptr, nxt, N, E);
  k_scatter<<<(E + 255) / 256, 256, 0, stream>>>(dst, nxt, order, E);

  k_conv<<<(N + 3) / 4, 256, 0, stream>>>(reads, conv_w, conv_b, h, N);
  k_edge_enc<<<(E * 16 + 255) / 256, 256, 0, stream>>>(sim, olen, We, be, e, E);

  for (int l = 0; l < 4; ++l) {
    k_node_gemm<<<dim3((N + 255) / 256, 3), 256, 0, stream>>>(
        h, A1 + l * 4096, A2 + l * 4096, V + l * 4096,
        bA1 + l * 64, bA2 + l * 64, bV + l * 64, XA1, XA2, XV, N);
    k_edge_compute<<<(E + 255) / 256, 256, 0, stream>>>(
        e, src, dst, XA1, XA2, A3 + l * 4096, bA3 + l * 64, ehat, E);
    k_aggregate<<<(N * 16 + 255) / 256, 256, 0, stream>>>(
        row_ptr, order, src, ehat, XV, numb, denb, N);
    k_hhat<<<(N + 255) / 256, 256, 0, stream>>>(
        h, U + l * 4096, bU + l * 64, numb, denb, hhat, N);
    hipMemsetAsync(sums, 0, sizeof(float) * 256, stream);
    k_stats<<<1024, 256, 0, stream>>>(ehat, E, sums);
    k_stats<<<256, 256, 0, stream>>>(hhat, N, sums + 128);
    k_finalize<<<1, 128, 0, stream>>>(sums, E, N, bneg + l * 64, bneb + l * 64,
                                      bnhg + l * 64, bnhb + l * 64, coef);
    k_update<<<(E * 16 + 255) / 256, 256, 0, stream>>>(e, ehat, coef, E);
    k_update<<<(N * 16 + 255) / 256, 256, 0, stream>>>(h, hhat, coef + 128, N);
  }

  k_decoder<<<(E + 255) / 256, 256, 0, stream>>>(h, e, src, dst, W1, b1, W2, b2, out, E);
}

// Round 2
// 2447.645 us; speedup vs baseline: 1.1722x; 1.1722x over previous
//
#include <hip/hip_runtime.h>
#include <hip/hip_bf16.h>
#include <cstdint>
#include <cstddef>

#define DD 64

typedef __attribute__((ext_vector_type(8))) short short8;
typedef __attribute__((ext_vector_type(4))) float f32x4;

__device__ __forceinline__ float4 f4_0() { return make_float4(0.f, 0.f, 0.f, 0.f); }

__device__ __forceinline__ unsigned short f2bf(float f) {
  __hip_bfloat16 h = __float2bfloat16(f);
  return *reinterpret_cast<unsigned short*>(&h);
}

// ---------- row GEMM: acc[d] += row[k] * W[k*64+d], k=0..63 ----------
__device__ __forceinline__ void row_gemm64(const float* __restrict__ row,
                                           const float* __restrict__ W,
                                           float acc[DD]) {
  for (int k4 = 0; k4 < DD; k4 += 4) {
    const float4 rv = *reinterpret_cast<const float4*>(row + k4);
    const float rvals[4] = {rv.x, rv.y, rv.z, rv.w};
#pragma unroll
    for (int kk = 0; kk < 4; ++kk) {
      const float v = rvals[kk];
      const float* wr = W + (k4 + kk) * DD;
#pragma unroll
      for (int d = 0; d < DD; ++d) acc[d] = fmaf(v, wr[d], acc[d]);
    }
  }
}

__device__ __forceinline__ void init_bias64(const float* __restrict__ b, float acc[DD]) {
#pragma unroll
  for (int d = 0; d < DD; ++d) acc[d] = b[d];
}

// ---------- CSR build ----------
__global__ __launch_bounds__(256) void k_hist(const int* __restrict__ dst,
                                              int* __restrict__ cnt, int E) {
  int j = blockIdx.x * 256 + threadIdx.x;
  if (j < E) atomicAdd(&cnt[dst[j]], 1);
}

// shfl-based single-block scan: 4 barriers per 1024-tile (was ~20)
__global__ __launch_bounds__(1024) void k_scan(const int* __restrict__ cnt,
                                               int* __restrict__ row_ptr,
                                               int* __restrict__ nxt, int N, int E) {
  __shared__ int wsum[16];
  __shared__ int carry_s;
  const int tid = threadIdx.x;
  const int wid = tid >> 6, lane = tid & 63;
  if (tid == 0) carry_s = 0;
  __syncthreads();
  const int nt = (N + 1023) / 1024;
  for (int b = 0; b < nt; ++b) {
    int i = b * 1024 + tid;
    int v = (i < N) ? cnt[i] : 0;
    int x = v;
#pragma unroll
    for (int off = 1; off < 64; off <<= 1) {
      int y = __shfl_up(x, off, 64);
      if (lane >= off) x += y;
    }
    if (lane == 63) wsum[wid] = x;
    __syncthreads();
    if (wid == 0 && lane < 16) {
      int wv = wsum[lane];
#pragma unroll
      for (int off = 1; off < 16; off <<= 1) {
        int y = __shfl_up(wv, off, 64);
        if (lane >= off) wv += y;
      }
      wsum[lane] = wv;
    }
    __syncthreads();
    int base = carry_s + (wid > 0 ? wsum[wid - 1] : 0);
    int excl = base + x - v;
    if (i < N) { row_ptr[i] = excl; nxt[i] = excl; }
    __syncthreads();
    if (tid == 0) carry_s += wsum[15];
    __syncthreads();
  }
  if (tid == 0) row_ptr[N] = E;
}

__global__ __launch_bounds__(256) void k_scatter(const int* __restrict__ dst,
                                                 int* __restrict__ nxt,
                                                 int* __restrict__ order, int E) {
  int j = blockIdx.x * 256 + threadIdx.x;
  if (j >= E) return;
  int pos = atomicAdd(&nxt[dst[j]], 1);
  order[pos] = j;
}

// ---------- conv1d (4->64, K=16, L=128, valid) + maxpool, via bf16 MFMA ----------
// Per node: D[d][t] = sum_k W[d][k] * B[k][t], K=64=(c,kk), B[k][t]=r[c][t+kk].
// LDS holds 4 shift-copies per channel: cp[s][q] = bf16(r[q+s]), so any lane's
// 8-consecutive-k fragment = two aligned ds_read_b64 from copy s = t&3.
// Max over t is permutation/padding-safe: t>=113 lanes masked; bias added post-max.
__global__ __launch_bounds__(256) void k_conv_mfma(const float* __restrict__ reads,
                                                   const float* __restrict__ w,
                                                   const float* __restrict__ bias,
                                                   float* __restrict__ h, int N) {
  __shared__ unsigned short cp[4 * 4 * 4 * 144];  // [node][c][s][144]
  const int tid = threadIdx.x;
  const int nb = blockIdx.x * 4;
  // --- staging: build shifted bf16 copies ---
  for (int task = tid; task < 576; task += 256) {
    const int node = task / 144;
    const int rem = task % 144;
    const int c = rem / 36;
    const int u = rem % 36;
    const int gn = nb + node;
    float4 v0 = f4_0(), v1 = f4_0();
    if (gn < N) {
      const float* rp = reads + (size_t)gn * 512 + c * 128 + 4 * u;
      if (u <= 31) v0 = *reinterpret_cast<const float4*>(rp);
      if (u <= 30) v1 = *reinterpret_cast<const float4*>(rp + 4);
    }
    unsigned short us[8];
    us[0] = f2bf(v0.x); us[1] = f2bf(v0.y); us[2] = f2bf(v0.z); us[3] = f2bf(v0.w);
    us[4] = f2bf(v1.x); us[5] = f2bf(v1.y); us[6] = f2bf(v1.z); us[7] = f2bf(v1.w);
    const int base = ((node * 4 + c) * 4) * 144 + 4 * u;
#pragma unroll
    for (int s = 0; s < 4; ++s) {
      uint2 pk;
      pk.x = (unsigned)us[s] | ((unsigned)us[s + 1] << 16);
      pk.y = (unsigned)us[s + 2] | ((unsigned)us[s + 3] << 16);
      *reinterpret_cast<uint2*>(&cp[base + s * 144]) = pk;
    }
  }
  __syncthreads();
  // --- MFMA phase: one wave per node ---
  const int wid = tid >> 6, lane = tid & 63;
  const int gn = nb + wid;
  if (gn >= N) return;
  const int col = lane & 15, grp = lane >> 4;
  // A fragments: lane holds W[row=col+16mt][kb..kb+7], kb = ks*32+grp*8
  short8 af[4][2];
#pragma unroll
  for (int mt = 0; mt < 4; ++mt)
#pragma unroll
    for (int ks = 0; ks < 2; ++ks) {
      const int d = col + 16 * mt;
      const int kb = ks * 32 + grp * 8;
      const float* wp = w + d * 64 + kb;
      float4 w0 = *reinterpret_cast<const float4*>(wp);
      float4 w1 = *reinterpret_cast<const float4*>(wp + 4);
      union { unsigned short us[8]; short8 v; } pk;
      pk.us[0] = f2bf(w0.x); pk.us[1] = f2bf(w0.y); pk.us[2] = f2bf(w0.z); pk.us[3] = f2bf(w0.w);
      pk.us[4] = f2bf(w1.x); pk.us[5] = f2bf(w1.y); pk.us[6] = f2bf(w1.z); pk.us[7] = f2bf(w1.w);
      af[mt][ks] = pk.v;
    }
  float vmax[4][4];
#pragma unroll
  for (int mt = 0; mt < 4; ++mt)
#pragma unroll
    for (int r = 0; r < 4; ++r) vmax[mt][r] = -3.0e38f;
  const int s = col & 3;  // t & 3 (nt*16 is 0 mod 4)
  for (int ntile = 0; ntile < 8; ++ntile) {
    const int t = ntile * 16 + col;
    f32x4 acc[4] = {};
#pragma unroll
    for (int ks = 0; ks < 2; ++ks) {
      const int kbase = ks * 32 + grp * 8;
      const int c = kbase >> 4;
      const int kk0 = kbase & 15;  // 0 or 8
      const int q = (t - s) + kk0; // %4 == 0 -> 8B-aligned bf16 chunks
      const unsigned short* p = &cp[((wid * 4 + c) * 4 + s) * 144 + q];
      uint2 lo = *reinterpret_cast<const uint2*>(p);
      uint2 hi = *reinterpret_cast<const uint2*>(p + 4);
      union { unsigned u[4]; short8 v; } bb;
      bb.u[0] = lo.x; bb.u[1] = lo.y; bb.u[2] = hi.x; bb.u[3] = hi.y;
#pragma unroll
      for (int mt = 0; mt < 4; ++mt)
        acc[mt] = __builtin_amdgcn_mfma_f32_16x16x32_bf16(af[mt][ks], bb.v, acc[mt], 0, 0, 0);
    }
    if (t < 113) {
#pragma unroll
      for (int mt = 0; mt < 4; ++mt)
#pragma unroll
        for (int r = 0; r < 4; ++r) vmax[mt][r] = fmaxf(vmax[mt][r], acc[mt][r]);
    }
  }
  // reduce max over the 16 column-lanes of each group
#pragma unroll
  for (int off = 8; off >= 1; off >>= 1)
#pragma unroll
    for (int mt = 0; mt < 4; ++mt)
#pragma unroll
      for (int r = 0; r < 4; ++r)
        vmax[mt][r] = fmaxf(vmax[mt][r], __shfl_xor(vmax[mt][r], off, 64));
  if (col == 0) {
#pragma unroll
    for (int mt = 0; mt < 4; ++mt)
#pragma unroll
      for (int r = 0; r < 4; ++r) {
        const int d = mt * 16 + grp * 4 + r;
        h[(size_t)gn * 64 + d] = vmax[mt][r] + bias[d];
      }
  }
}

// ---------- edge encoder ----------
__global__ __launch_bounds__(256) void k_edge_enc(const float* __restrict__ sim,
                                                  const float* __restrict__ len,
                                                  const float* __restrict__ We,
                                                  const float* __restrict__ be,
                                                  float* __restrict__ e, int E) {
  int idx = blockIdx.x * 256 + threadIdx.x;
  if (idx >= E * 16) return;
  int j = idx >> 4, dc = (idx & 15) << 2;
  float s = sim[j], L = len[j];
  float4 w0 = *reinterpret_cast<const float4*>(We + dc);
  float4 w1 = *reinterpret_cast<const float4*>(We + 64 + dc);
  float4 b  = *reinterpret_cast<const float4*>(be + dc);
  float4 o;
  o.x = fmaf(s, w0.x, fmaf(L, w1.x, b.x));
  o.y = fmaf(s, w0.y, fmaf(L, w1.y, b.y));
  o.z = fmaf(s, w0.z, fmaf(L, w1.z, b.z));
  o.w = fmaf(s, w0.w, fmaf(L, w1.w, b.w));
  *reinterpret_cast<float4*>(e + (size_t)j * 64 + dc) = o;
}

// ---------- node GEMMs ----------
__global__ __launch_bounds__(256) void k_node_gemm(const float* __restrict__ h,
                                                   const float* __restrict__ Wa,
                                                   const float* __restrict__ Wb,
                                                   const float* __restrict__ Wc,
                                                   const float* __restrict__ ba,
                                                   const float* __restrict__ bb,
                                                   const float* __restrict__ bc,
                                                   float* __restrict__ Xa,
                                                   float* __restrict__ Xb,
                                                   float* __restrict__ Xc, int N) {
  const float* W; const float* bi; float* X;
  if (blockIdx.y == 0)      { W = Wa; bi = ba; X = Xa; }
  else if (blockIdx.y == 1) { W = Wb; bi = bb; X = Xb; }
  else                      { W = Wc; bi = bc; X = Xc; }
  int n = blockIdx.x * 256 + threadIdx.x;
  if (n >= N) return;
  float acc[DD];
  init_bias64(bi, acc);
  row_gemm64(h + (size_t)n * 64, W, acc);
#pragma unroll
  for (int dc = 0; dc < DD; dc += 4) {
    float4 v = make_float4(acc[dc], acc[dc + 1], acc[dc + 2], acc[dc + 3]);
    *reinterpret_cast<float4*>(X + (size_t)n * 64 + dc) = v;
  }
}

// ---------- edge compute ----------
__global__ __launch_bounds__(256) void k_edge_compute(const float* __restrict__ e,
                                                      const int* __restrict__ src,
                                                      const int* __restrict__ dst,
                                                      const float* __restrict__ XA1,
                                                      const float* __restrict__ XA2,
                                                      const float* __restrict__ A3,
                                                      const float* __restrict__ bA3,
                                                      float* __restrict__ ehat, int E) {
  int j = blockIdx.x * 256 + threadIdx.x;
  if (j >= E) return;
  float acc[DD];
  init_bias64(bA3, acc);
  row_gemm64(e + (size_t)j * 64, A3, acc);
  int s = src[j], t = dst[j];
#pragma unroll
  for (int dc = 0; dc < DD; dc += 4) {
    float4 a = *reinterpret_cast<const float4*>(XA1 + (size_t)s * 64 + dc);
    float4 b = *reinterpret_cast<const float4*>(XA2 + (size_t)t * 64 + dc);
    float4 o = make_float4(acc[dc] + a.x + b.x, acc[dc + 1] + a.y + b.y,
                           acc[dc + 2] + a.z + b.z, acc[dc + 3] + a.w + b.w);
    *reinterpret_cast<float4*>(ehat + (size_t)j * 64 + dc) = o;
  }
}

// ---------- fused aggregation + e-update ----------
// num = sum sigma*XV[src]; den = sum sigma; e[eid] += relu(sc*ehat+sh)
__global__ __launch_bounds__(256) void k_aggregate_upd(const int* __restrict__ row_ptr,
                                                       const int* __restrict__ order,
                                                       const int* __restrict__ src,
                                                       const float* __restrict__ ehat,
                                                       const float* __restrict__ XV,
                                                       const float* __restrict__ coef_e,
                                                       float* __restrict__ e,
                                                       float* __restrict__ num,
                                                       float* __restrict__ den, int N) {
  int idx = blockIdx.x * 256 + threadIdx.x;
  if (idx >= N * 16) return;
  int n = idx >> 4, dc = (idx & 15) << 2;
  int beg = row_ptr[n], end = row_ptr[n + 1];
  float4 sc = *reinterpret_cast<const float4*>(coef_e + dc);
  float4 sh = *reinterpret_cast<const float4*>(coef_e + 64 + dc);
  float4 nm = f4_0(), dn = f4_0();
  for (int i = beg; i < end; ++i) {
    int eid = order[i];
    int sj = src[eid];
    size_t eoff = (size_t)eid * 64 + dc;
    float4 eh = *reinterpret_cast<const float4*>(ehat + eoff);
    float4 vv = *reinterpret_cast<const float4*>(XV + (size_t)sj * 64 + dc);
    float4 sg;
    sg.x = 1.f / (1.f + __expf(-eh.x));
    sg.y = 1.f / (1.f + __expf(-eh.y));
    sg.z = 1.f / (1.f + __expf(-eh.z));
    sg.w = 1.f / (1.f + __expf(-eh.w));
    dn.x += sg.x; dn.y += sg.y; dn.z += sg.z; dn.w += sg.w;
    nm.x = fmaf(sg.x, vv.x, nm.x); nm.y = fmaf(sg.y, vv.y, nm.y);
    nm.z = fmaf(sg.z, vv.z, nm.z); nm.w = fmaf(sg.w, vv.w, nm.w);
    float4 ev = *reinterpret_cast<const float4*>(e + eoff);
    ev.x += fmaxf(fmaf(sc.x, eh.x, sh.x), 0.f);
    ev.y += fmaxf(fmaf(sc.y, eh.y, sh.y), 0.f);
    ev.z += fmaxf(fmaf(sc.z, eh.z, sh.z), 0.f);
    ev.w += fmaxf(fmaf(sc.w, eh.w, sh.w), 0.f);
    *reinterpret_cast<float4*>(e + eoff) = ev;
  }
  *reinterpret_cast<float4*>(num + (size_t)n * 64 + dc) = nm;
  *reinterpret_cast<float4*>(den + (size_t)n * 64 + dc) = dn;
}

// ---------- h_hat ----------
__global__ __launch_bounds__(256) void k_hhat(const float* __restrict__ h,
                                              const float* __restrict__ Uw,
                                              const float* __restrict__ bU,
                                              const float* __restrict__ num,
                                              const float* __restrict__ den,
                                              float* __restrict__ hhat, int N) {
  int n = blockIdx.x * 256 + threadIdx.x;
  if (n >= N) return;
  float acc[DD];
  init_bias64(bU, acc);
  row_gemm64(h + (size_t)n * 64, Uw, acc);
#pragma unroll
  for (int dc = 0; dc < DD; dc += 4) {
    float4 nm = *reinterpret_cast<const float4*>(num + (size_t)n * 64 + dc);
    float4 dn = *reinterpret_cast<const float4*>(den + (size_t)n * 64 + dc);
    float4 o = make_float4(acc[dc] + nm.x / (dn.x + 1e-6f),
                           acc[dc + 1] + nm.y / (dn.y + 1e-6f),
                           acc[dc + 2] + nm.z / (dn.z + 1e-6f),
                           acc[dc + 3] + nm.w / (dn.w + 1e-6f));
    *reinterpret_cast<float4*>(hhat + (size_t)n * 64 + dc) = o;
  }
}

// ---------- per-channel sum & sumsq ----------
__global__ __launch_bounds__(256) void k_stats(const float* __restrict__ X, int R,
                                               float* __restrict__ sums) {
  __shared__ float red[2][16][64];
  int tid = threadIdx.x;
  int g = tid >> 4, dc = (tid & 15) << 2;
  float4 s = f4_0(), q = f4_0();
  for (int r = blockIdx.x * 16 + g; r < R; r += gridDim.x * 16) {
    float4 v = *reinterpret_cast<const float4*>(X + (size_t)r * 64 + dc);
    s.x += v.x; s.y += v.y; s.z += v.z; s.w += v.w;
    q.x = fmaf(v.x, v.x, q.x); q.y = fmaf(v.y, v.y, q.y);
    q.z = fmaf(v.z, v.z, q.z); q.w = fmaf(v.w, v.w, q.w);
  }
  *reinterpret_cast<float4*>(&red[0][g][dc]) = s;
  *reinterpret_cast<float4*>(&red[1][g][dc]) = q;
  __syncthreads();
  if (g == 0) {
    float4 ts = f4_0(), tq = f4_0();
#pragma unroll
    for (int gg = 0; gg < 16; ++gg) {
      float4 a = *reinterpret_cast<const float4*>(&red[0][gg][dc]);
      float4 b = *reinterpret_cast<const float4*>(&red[1][gg][dc]);
      ts.x += a.x; ts.y += a.y; ts.z += a.z; ts.w += a.w;
      tq.x += b.x; tq.y += b.y; tq.z += b.z; tq.w += b.w;
    }
    atomicAdd(&sums[dc], ts.x); atomicAdd(&sums[dc + 1], ts.y);
    atomicAdd(&sums[dc + 2], ts.z); atomicAdd(&sums[dc + 3], ts.w);
    atomicAdd(&sums[64 + dc], tq.x); atomicAdd(&sums[64 + dc + 1], tq.y);
    atomicAdd(&sums[64 + dc + 2], tq.z); atomicAdd(&sums[64 + dc + 3], tq.w);
  }
}

// ---------- fold BN stats into scale/shift (64-ch block) ----------
__global__ void k_finalize(const float* __restrict__ sums, int R,
                           const float* __restrict__ gamma,
                           const float* __restrict__ beta,
                           float* __restrict__ coef) {
  int t = threadIdx.x;
  if (t < 64) {
    float mean = sums[t] / (float)R;
    float var = sums[64 + t] / (float)R - mean * mean;
    float sc = gamma[t] * rsqrtf(var + 1e-5f);
    coef[t] = sc;
    coef[64 + t] = beta[t] - mean * sc;
  }
}

// ---------- X += relu(scale*Y + shift) ----------
__global__ __launch_bounds__(256) void k_update(float* __restrict__ X,
                                                const float* __restrict__ Y,
                                                const float* __restrict__ coef, int R) {
  int idx = blockIdx.x * 256 + threadIdx.x;
  if (idx >= R * 16) return;
  int r = idx >> 4, dc = (idx & 15) << 2;
  float4 sc = *reinterpret_cast<const float4*>(coef + dc);
  float4 sh = *reinterpret_cast<const float4*>(coef + 64 + dc);
  size_t off = (size_t)r * 64 + dc;
  float4 y = *reinterpret_cast<const float4*>(Y + off);
  float4 x = *reinterpret_cast<const float4*>(X + off);
  x.x += fmaxf(fmaf(sc.x, y.x, sh.x), 0.f);
  x.y += fmaxf(fmaf(sc.y, y.y, sh.y), 0.f);
  x.z += fmaxf(fmaf(sc.z, y.z, sh.z), 0.f);
  x.w += fmaxf(fmaf(sc.w, y.w, sh.w), 0.f);
  *reinterpret_cast<float4*>(X + off) = x;
}

// ---------- decoder ----------
__global__ __launch_bounds__(256) void k_decoder(const float* __restrict__ h,
                                                 const float* __restrict__ e,
                                                 const int* __restrict__ src,
                                                 const int* __restrict__ dst,
                                                 const float* __restrict__ W1,
                                                 const float* __restrict__ b1,
                                                 const float* __restrict__ W2,
                                                 const float* __restrict__ b2,
                                                 float* __restrict__ out, int E) {
  int j = blockIdx.x * 256 + threadIdx.x;
  if (j >= E) return;
  int s = src[j], t = dst[j];
  float acc[DD];
  init_bias64(b1, acc);
  row_gemm64(h + (size_t)s * 64, W1, acc);
  row_gemm64(h + (size_t)t * 64, W1 + 64 * 64, acc);
  row_gemm64(e + (size_t)j * 64, W1 + 128 * 64, acc);
  float p = b2[0];
#pragma unroll
  for (int d = 0; d < DD; ++d) p = fmaf(fmaxf(acc[d], 0.f), W2[d], p);
  out[j] = p;
}

extern "C" void kernel_launch(void* const* d_in, const int* in_sizes, int n_in,
                              void* d_out, int out_size, void* d_ws, size_t ws_size,
                              hipStream_t stream) {
  const float* reads  = (const float*)d_in[0];
  const int*   src    = (const int*)d_in[1];
  const int*   dst    = (const int*)d_in[2];
  const float* sim    = (const float*)d_in[3];
  const float* olen   = (const float*)d_in[4];
  const float* conv_w = (const float*)d_in[5];
  const float* conv_b = (const float*)d_in[6];
  const float* We     = (const float*)d_in[7];
  const float* be     = (const float*)d_in[8];
  const float* A1     = (const float*)d_in[9];
  const float* A2     = (const float*)d_in[10];
  const float* A3     = (const float*)d_in[11];
  const float* bA1    = (const float*)d_in[12];
  const float* bA2    = (const float*)d_in[13];
  const float* bA3    = (const float*)d_in[14];
  const float* U      = (const float*)d_in[15];
  const float* V      = (const float*)d_in[16];
  const float* bU     = (const float*)d_in[17];
  const float* bV     = (const float*)d_in[18];
  const float* bnhg   = (const float*)d_in[19];
  const float* bnhb   = (const float*)d_in[20];
  const float* bneg   = (const float*)d_in[21];
  const float* bneb   = (const float*)d_in[22];
  const float* W1     = (const float*)d_in[23];
  const float* b1     = (const float*)d_in[24];
  const float* W2     = (const float*)d_in[25];
  const float* b2     = (const float*)d_in[26];

  const int N = in_sizes[0] / 512;   // reads: [N,4,128]
  const int E = in_sizes[1];

  float* p = (float*)d_ws;
  float* h    = p; p += (size_t)N * 64;
  float* e    = p; p += (size_t)E * 64;
  float* ehat = p; p += (size_t)E * 64;
  float* XA1  = p; p += (size_t)N * 64;
  float* XA2  = p; p += (size_t)N * 64;
  float* XV   = p; p += (size_t)N * 64;
  float* hhat = p; p += (size_t)N * 64;
  float* numb = p; p += (size_t)N * 64;
  float* denb = p; p += (size_t)N * 64;
  float* sums = p; p += 256;
  float* coef = p; p += 256;
  int* ip = (int*)p;
  int* cnt     = ip; ip += N;
  int* row_ptr = ip; ip += N + 1;
  int* nxt     = ip; ip += N;
  int* order   = ip; ip += E;
  float* out = (float*)d_out;

  // CSR of dst
  hipMemsetAsync(cnt, 0, sizeof(int) * N, stream);
  k_hist<<<(E + 255) / 256, 256, 0, stream>>>(dst, cnt, E);
  k_scan<<<1, 1024, 0, stream>>>(cnt, row_ptr, nxt, N, E);
  k_scatter<<<(E + 255) / 256, 256, 0, stream>>>(dst, nxt, order, E);

  k_conv_mfma<<<(N + 3) / 4, 256, 0, stream>>>(reads, conv_w, conv_b, h, N);
  k_edge_enc<<<(E * 16 + 255) / 256, 256, 0, stream>>>(sim, olen, We, be, e, E);

  for (int l = 0; l < 4; ++l) {
    k_node_gemm<<<dim3((N + 255) / 256, 3), 256, 0, stream>>>(
        h, A1 + l * 4096, A2 + l * 4096, V + l * 4096,
        bA1 + l * 64, bA2 + l * 64, bV + l * 64, XA1, XA2, XV, N);
    k_edge_compute<<<(E + 255) / 256, 256, 0, stream>>>(
        e, src, dst, XA1, XA2, A3 + l * 4096, bA3 + l * 64, ehat, E);
    hipMemsetAsync(sums, 0, sizeof(float) * 256, stream);
    k_stats<<<1024, 256, 0, stream>>>(ehat, E, sums);
    k_finalize<<<1, 64, 0, stream>>>(sums, E, bneg + l * 64, bneb + l * 64, coef);
    k_aggregate_upd<<<(N * 16 + 255) / 256, 256, 0, stream>>>(
        row_ptr, order, src, ehat, XV, coef, e, numb, denb, N);
    k_hhat<<<(N + 255) / 256, 256, 0, stream>>>(
        h, U + l * 4096, bU + l * 64, numb, denb, hhat, N);
    k_stats<<<256, 256, 0, stream>>>(hhat, N, sums + 128);
    k_finalize<<<1, 64, 0, stream>>>(sums + 128, N, bnhg + l * 64, bnhb + l * 64, coef + 128);
    k_update<<<(N * 16 + 255) / 256, 256, 0, stream>>>(h, hhat, coef + 128, N);
  }

  k_decoder<<<(E + 255) / 256, 256, 0, stream>>>(h, e, src, dst, W1, b1, W2, b2, out, E);
}

// Round 3
// 1805.928 us; speedup vs baseline: 1.5887x; 1.3553x over previous
//
#include <hip/hip_runtime.h>
#include <hip/hip_bf16.h>
#include <cstdint>
#include <cstddef>

#define DD 64

typedef __attribute__((ext_vector_type(8))) short short8;
typedef __attribute__((ext_vector_type(4))) float f32x4;

__device__ __forceinline__ float4 f4_0() { return make_float4(0.f, 0.f, 0.f, 0.f); }

__device__ __forceinline__ unsigned short f2bf(float f) {
  __hip_bfloat16 h = __float2bfloat16(f);
  return *reinterpret_cast<unsigned short*>(&h);
}

__device__ __forceinline__ short8 pack_bf16x8(float4 a, float4 b) {
  union { unsigned short us[8]; short8 v; } pk;
  pk.us[0] = f2bf(a.x); pk.us[1] = f2bf(a.y); pk.us[2] = f2bf(a.z); pk.us[3] = f2bf(a.w);
  pk.us[4] = f2bf(b.x); pk.us[5] = f2bf(b.y); pk.us[6] = f2bf(b.z); pk.us[7] = f2bf(b.w);
  return pk.v;
}

// ---------- row GEMM (fp32, node-side): acc[d] += row[k] * W[k*64+d] ----------
__device__ __forceinline__ void row_gemm64(const float* __restrict__ row,
                                           const float* __restrict__ W,
                                           float acc[DD]) {
  for (int k4 = 0; k4 < DD; k4 += 4) {
    const float4 rv = *reinterpret_cast<const float4*>(row + k4);
    const float rvals[4] = {rv.x, rv.y, rv.z, rv.w};
#pragma unroll
    for (int kk = 0; kk < 4; ++kk) {
      const float v = rvals[kk];
      const float* wr = W + (k4 + kk) * DD;
#pragma unroll
      for (int d = 0; d < DD; ++d) acc[d] = fmaf(v, wr[d], acc[d]);
    }
  }
}

__device__ __forceinline__ void init_bias64(const float* __restrict__ b, float acc[DD]) {
#pragma unroll
  for (int d = 0; d < DD; ++d) acc[d] = b[d];
}

// ---------- CSR build ----------
__global__ __launch_bounds__(256) void k_hist(const int* __restrict__ dst,
                                              int* __restrict__ cnt, int E) {
  int j = blockIdx.x * 256 + threadIdx.x;
  if (j < E) atomicAdd(&cnt[dst[j]], 1);
}

__global__ __launch_bounds__(1024) void k_scan(const int* __restrict__ cnt,
                                               int* __restrict__ row_ptr,
                                               int* __restrict__ nxt, int N, int E) {
  __shared__ int wsum[16];
  __shared__ int carry_s;
  const int tid = threadIdx.x;
  const int wid = tid >> 6, lane = tid & 63;
  if (tid == 0) carry_s = 0;
  __syncthreads();
  const int nt = (N + 1023) / 1024;
  for (int b = 0; b < nt; ++b) {
    int i = b * 1024 + tid;
    int v = (i < N) ? cnt[i] : 0;
    int x = v;
#pragma unroll
    for (int off = 1; off < 64; off <<= 1) {
      int y = __shfl_up(x, off, 64);
      if (lane >= off) x += y;
    }
    if (lane == 63) wsum[wid] = x;
    __syncthreads();
    if (wid == 0 && lane < 16) {
      int wv = wsum[lane];
#pragma unroll
      for (int off = 1; off < 16; off <<= 1) {
        int y = __shfl_up(wv, off, 64);
        if (lane >= off) wv += y;
      }
      wsum[lane] = wv;
    }
    __syncthreads();
    int base = carry_s + (wid > 0 ? wsum[wid - 1] : 0);
    int excl = base + x - v;
    if (i < N) { row_ptr[i] = excl; nxt[i] = excl; }
    __syncthreads();
    if (tid == 0) carry_s += wsum[15];
    __syncthreads();
  }
  if (tid == 0) row_ptr[N] = E;
}

__global__ __launch_bounds__(256) void k_scatter(const int* __restrict__ dst,
                                                 int* __restrict__ nxt,
                                                 int* __restrict__ order, int E) {
  int j = blockIdx.x * 256 + threadIdx.x;
  if (j >= E) return;
  int pos = atomicAdd(&nxt[dst[j]], 1);
  order[pos] = j;
}

// ---------- conv1d + maxpool via bf16 MFMA (round-2 kernel, verified) ----------
__global__ __launch_bounds__(256) void k_conv_mfma(const float* __restrict__ reads,
                                                   const float* __restrict__ w,
                                                   const float* __restrict__ bias,
                                                   float* __restrict__ h, int N) {
  __shared__ unsigned short cp[4 * 4 * 4 * 144];  // [node][c][s][144]
  const int tid = threadIdx.x;
  const int nb = blockIdx.x * 4;
  for (int task = tid; task < 576; task += 256) {
    const int node = task / 144;
    const int rem = task % 144;
    const int c = rem / 36;
    const int u = rem % 36;
    const int gn = nb + node;
    float4 v0 = f4_0(), v1 = f4_0();
    if (gn < N) {
      const float* rp = reads + (size_t)gn * 512 + c * 128 + 4 * u;
      if (u <= 31) v0 = *reinterpret_cast<const float4*>(rp);
      if (u <= 30) v1 = *reinterpret_cast<const float4*>(rp + 4);
    }
    unsigned short us[8];
    us[0] = f2bf(v0.x); us[1] = f2bf(v0.y); us[2] = f2bf(v0.z); us[3] = f2bf(v0.w);
    us[4] = f2bf(v1.x); us[5] = f2bf(v1.y); us[6] = f2bf(v1.z); us[7] = f2bf(v1.w);
    const int base = ((node * 4 + c) * 4) * 144 + 4 * u;
#pragma unroll
    for (int s = 0; s < 4; ++s) {
      uint2 pk;
      pk.x = (unsigned)us[s] | ((unsigned)us[s + 1] << 16);
      pk.y = (unsigned)us[s + 2] | ((unsigned)us[s + 3] << 16);
      *reinterpret_cast<uint2*>(&cp[base + s * 144]) = pk;
    }
  }
  __syncthreads();
  const int wid = tid >> 6, lane = tid & 63;
  const int gn = nb + wid;
  if (gn >= N) return;
  const int col = lane & 15, grp = lane >> 4;
  short8 af[4][2];
#pragma unroll
  for (int mt = 0; mt < 4; ++mt)
#pragma unroll
    for (int ks = 0; ks < 2; ++ks) {
      const int d = col + 16 * mt;
      const int kb = ks * 32 + grp * 8;
      const float* wp = w + d * 64 + kb;
      float4 w0 = *reinterpret_cast<const float4*>(wp);
      float4 w1 = *reinterpret_cast<const float4*>(wp + 4);
      af[mt][ks] = pack_bf16x8(w0, w1);
    }
  float vmax[4][4];
#pragma unroll
  for (int mt = 0; mt < 4; ++mt)
#pragma unroll
    for (int r = 0; r < 4; ++r) vmax[mt][r] = -3.0e38f;
  const int s = col & 3;
  for (int ntile = 0; ntile < 8; ++ntile) {
    const int t = ntile * 16 + col;
    f32x4 acc[4] = {};
#pragma unroll
    for (int ks = 0; ks < 2; ++ks) {
      const int kbase = ks * 32 + grp * 8;
      const int c = kbase >> 4;
      const int kk0 = kbase & 15;
      const int q = (t - s) + kk0;
      const unsigned short* p = &cp[((wid * 4 + c) * 4 + s) * 144 + q];
      uint2 lo = *reinterpret_cast<const uint2*>(p);
      uint2 hi = *reinterpret_cast<const uint2*>(p + 4);
      union { unsigned u[4]; short8 v; } bb;
      bb.u[0] = lo.x; bb.u[1] = lo.y; bb.u[2] = hi.x; bb.u[3] = hi.y;
#pragma unroll
      for (int mt = 0; mt < 4; ++mt)
        acc[mt] = __builtin_amdgcn_mfma_f32_16x16x32_bf16(af[mt][ks], bb.v, acc[mt], 0, 0, 0);
    }
    if (t < 113) {
#pragma unroll
      for (int mt = 0; mt < 4; ++mt)
#pragma unroll
        for (int r = 0; r < 4; ++r) vmax[mt][r] = fmaxf(vmax[mt][r], acc[mt][r]);
    }
  }
#pragma unroll
  for (int off = 8; off >= 1; off >>= 1)
#pragma unroll
    for (int mt = 0; mt < 4; ++mt)
#pragma unroll
      for (int r = 0; r < 4; ++r)
        vmax[mt][r] = fmaxf(vmax[mt][r], __shfl_xor(vmax[mt][r], off, 64));
  if (col == 0) {
#pragma unroll
    for (int mt = 0; mt < 4; ++mt)
#pragma unroll
      for (int r = 0; r < 4; ++r) {
        const int d = mt * 16 + grp * 4 + r;
        h[(size_t)gn * 64 + d] = vmax[mt][r] + bias[d];
      }
  }
}

// ---------- edge encoder ----------
__global__ __launch_bounds__(256) void k_edge_enc(const float* __restrict__ sim,
                                                  const float* __restrict__ len,
                                                  const float* __restrict__ We,
                                                  const float* __restrict__ be,
                                                  float* __restrict__ e, int E) {
  int idx = blockIdx.x * 256 + threadIdx.x;
  if (idx >= E * 16) return;
  int j = idx >> 4, dc = (idx & 15) << 2;
  float s = sim[j], L = len[j];
  float4 w0 = *reinterpret_cast<const float4*>(We + dc);
  float4 w1 = *reinterpret_cast<const float4*>(We + 64 + dc);
  float4 b  = *reinterpret_cast<const float4*>(be + dc);
  float4 o;
  o.x = fmaf(s, w0.x, fmaf(L, w1.x, b.x));
  o.y = fmaf(s, w0.y, fmaf(L, w1.y, b.y));
  o.z = fmaf(s, w0.z, fmaf(L, w1.z, b.z));
  o.w = fmaf(s, w0.w, fmaf(L, w1.w, b.w));
  *reinterpret_cast<float4*>(e + (size_t)j * 64 + dc) = o;
}

// ---------- node GEMMs (fp32) ----------
__global__ __launch_bounds__(256) void k_node_gemm(const float* __restrict__ h,
                                                   const float* __restrict__ Wa,
                                                   const float* __restrict__ Wb,
                                                   const float* __restrict__ Wc,
                                                   const float* __restrict__ ba,
                                                   const float* __restrict__ bb,
                                                   const float* __restrict__ bc,
                                                   float* __restrict__ Xa,
                                                   float* __restrict__ Xb,
                                                   float* __restrict__ Xc, int N) {
  const float* W; const float* bi; float* X;
  if (blockIdx.y == 0)      { W = Wa; bi = ba; X = Xa; }
  else if (blockIdx.y == 1) { W = Wb; bi = bb; X = Xb; }
  else                      { W = Wc; bi = bc; X = Xc; }
  int n = blockIdx.x * 256 + threadIdx.x;
  if (n >= N) return;
  float acc[DD];
  init_bias64(bi, acc);
  row_gemm64(h + (size_t)n * 64, W, acc);
#pragma unroll
  for (int dc = 0; dc < DD; dc += 4) {
    float4 v = make_float4(acc[dc], acc[dc + 1], acc[dc + 2], acc[dc + 3]);
    *reinterpret_cast<float4*>(X + (size_t)n * 64 + dc) = v;
  }
}

// ---------- edge compute via MFMA, swapped operands, fused BN stats ----------
// D[ch][edge] = (A3^T @ e^T): A-frag rows = output channels, B-frag cols = edges.
// Each lane then owns contiguous ch-quads of ONE edge -> float4 gathers/stores.
__global__ __launch_bounds__(256) void k_edge_mfma(const float* __restrict__ e,
                                                   const int* __restrict__ src,
                                                   const int* __restrict__ dst,
                                                   const float* __restrict__ XA1,
                                                   const float* __restrict__ XA2,
                                                   const float* __restrict__ A3,
                                                   const float* __restrict__ bA3,
                                                   float* __restrict__ ehat,
                                                   float* __restrict__ sums, int E) {
  __shared__ unsigned short At[64 * 72];  // At[n][k] = A3[k][n], stride 72 (2-way banks)
  __shared__ float s_sums[128];
  const int tid = threadIdx.x;
  if (tid < 128) s_sums[tid] = 0.f;
  for (int i = tid; i < 4096; i += 256) {
    int n = i & 63, k = i >> 6;
    At[n * 72 + k] = f2bf(A3[k * 64 + n]);
  }
  __syncthreads();
  const int wid = tid >> 6, lane = tid & 63;
  const int col = lane & 15, g = lane >> 4;
  const int eb = (blockIdx.x * 4 + wid) * 16;
  int edge = eb + col;
  const bool valid = edge < E;
  if (!valid) edge = E - 1;
  const int se = src[edge], de = dst[edge];
  f32x4 acc[4] = {};
#pragma unroll
  for (int ks = 0; ks < 2; ++ks) {
    const float* bp = e + (size_t)edge * 64 + ks * 32 + g * 8;
    float4 b0 = *reinterpret_cast<const float4*>(bp);
    float4 b1v = *reinterpret_cast<const float4*>(bp + 4);
    short8 bfr = pack_bf16x8(b0, b1v);
#pragma unroll
    for (int mt = 0; mt < 4; ++mt) {
      const unsigned short* ap = &At[(mt * 16 + col) * 72 + ks * 32 + g * 8];
      uint2 lo = *reinterpret_cast<const uint2*>(ap);
      uint2 hi = *reinterpret_cast<const uint2*>(ap + 4);
      union { unsigned u[4]; short8 v; } aa;
      aa.u[0] = lo.x; aa.u[1] = lo.y; aa.u[2] = hi.x; aa.u[3] = hi.y;
      acc[mt] = __builtin_amdgcn_mfma_f32_16x16x32_bf16(aa.v, bfr, acc[mt], 0, 0, 0);
    }
  }
  // epilogue: add gathered node terms + bias; store; accumulate BN stats
#pragma unroll
  for (int mt = 0; mt < 4; ++mt) {
    const int chb = mt * 16 + g * 4;
    float4 x1 = *reinterpret_cast<const float4*>(XA1 + (size_t)se * 64 + chb);
    float4 x2 = *reinterpret_cast<const float4*>(XA2 + (size_t)de * 64 + chb);
    float4 ba = *reinterpret_cast<const float4*>(bA3 + chb);
    float o[4];
    o[0] = acc[mt][0] + x1.x + x2.x + ba.x;
    o[1] = acc[mt][1] + x1.y + x2.y + ba.y;
    o[2] = acc[mt][2] + x1.z + x2.z + ba.z;
    o[3] = acc[mt][3] + x1.w + x2.w + ba.w;
    if (valid) {
      float4 ov = make_float4(o[0], o[1], o[2], o[3]);
      *reinterpret_cast<float4*>(ehat + (size_t)edge * 64 + chb) = ov;
    }
#pragma unroll
    for (int c = 0; c < 4; ++c) {
      float sv = valid ? o[c] : 0.f;
      float qv = sv * sv;
#pragma unroll
      for (int off = 1; off <= 8; off <<= 1) {
        sv += __shfl_xor(sv, off, 64);
        qv += __shfl_xor(qv, off, 64);
      }
      if (col == 0) {
        atomicAdd(&s_sums[chb + c], sv);
        atomicAdd(&s_sums[64 + chb + c], qv);
      }
    }
  }
  __syncthreads();
  if (tid < 128) atomicAdd(&sums[tid], s_sums[tid]);
}

// ---------- fused aggregation + e-update ----------
__global__ __launch_bounds__(256) void k_aggregate_upd(const int* __restrict__ row_ptr,
                                                       const int* __restrict__ order,
                                                       const int* __restrict__ src,
                                                       const float* __restrict__ ehat,
                                                       const float* __restrict__ XV,
                                                       const float* __restrict__ coef_e,
                                                       float* __restrict__ e,
                                                       float* __restrict__ num,
                                                       float* __restrict__ den, int N) {
  int idx = blockIdx.x * 256 + threadIdx.x;
  if (idx >= N * 16) return;
  int n = idx >> 4, dc = (idx & 15) << 2;
  int beg = row_ptr[n], end = row_ptr[n + 1];
  float4 sc = *reinterpret_cast<const float4*>(coef_e + dc);
  float4 sh = *reinterpret_cast<const float4*>(coef_e + 64 + dc);
  float4 nm = f4_0(), dn = f4_0();
  for (int i = beg; i < end; ++i) {
    int eid = order[i];
    int sj = src[eid];
    size_t eoff = (size_t)eid * 64 + dc;
    float4 eh = *reinterpret_cast<const float4*>(ehat + eoff);
    float4 vv = *reinterpret_cast<const float4*>(XV + (size_t)sj * 64 + dc);
    float4 sg;
    sg.x = 1.f / (1.f + __expf(-eh.x));
    sg.y = 1.f / (1.f + __expf(-eh.y));
    sg.z = 1.f / (1.f + __expf(-eh.z));
    sg.w = 1.f / (1.f + __expf(-eh.w));
    dn.x += sg.x; dn.y += sg.y; dn.z += sg.z; dn.w += sg.w;
    nm.x = fmaf(sg.x, vv.x, nm.x); nm.y = fmaf(sg.y, vv.y, nm.y);
    nm.z = fmaf(sg.z, vv.z, nm.z); nm.w = fmaf(sg.w, vv.w, nm.w);
    float4 ev = *reinterpret_cast<const float4*>(e + eoff);
    ev.x += fmaxf(fmaf(sc.x, eh.x, sh.x), 0.f);
    ev.y += fmaxf(fmaf(sc.y, eh.y, sh.y), 0.f);
    ev.z += fmaxf(fmaf(sc.z, eh.z, sh.z), 0.f);
    ev.w += fmaxf(fmaf(sc.w, eh.w, sh.w), 0.f);
    *reinterpret_cast<float4*>(e + eoff) = ev;
  }
  *reinterpret_cast<float4*>(num + (size_t)n * 64 + dc) = nm;
  *reinterpret_cast<float4*>(den + (size_t)n * 64 + dc) = dn;
}

// ---------- h_hat (fp32) ----------
__global__ __launch_bounds__(256) void k_hhat(const float* __restrict__ h,
                                              const float* __restrict__ Uw,
                                              const float* __restrict__ bU,
                                              const float* __restrict__ num,
                                              const float* __restrict__ den,
                                              float* __restrict__ hhat, int N) {
  int n = blockIdx.x * 256 + threadIdx.x;
  if (n >= N) return;
  float acc[DD];
  init_bias64(bU, acc);
  row_gemm64(h + (size_t)n * 64, Uw, acc);
#pragma unroll
  for (int dc = 0; dc < DD; dc += 4) {
    float4 nm = *reinterpret_cast<const float4*>(num + (size_t)n * 64 + dc);
    float4 dn = *reinterpret_cast<const float4*>(den + (size_t)n * 64 + dc);
    float4 o = make_float4(acc[dc] + nm.x / (dn.x + 1e-6f),
                           acc[dc + 1] + nm.y / (dn.y + 1e-6f),
                           acc[dc + 2] + nm.z / (dn.z + 1e-6f),
                           acc[dc + 3] + nm.w / (dn.w + 1e-6f));
    *reinterpret_cast<float4*>(hhat + (size_t)n * 64 + dc) = o;
  }
}

// ---------- per-channel sum & sumsq (used for hhat only now) ----------
__global__ __launch_bounds__(256) void k_stats(const float* __restrict__ X, int R,
                                               float* __restrict__ sums) {
  __shared__ float red[2][16][64];
  int tid = threadIdx.x;
  int g = tid >> 4, dc = (tid & 15) << 2;
  float4 s = f4_0(), q = f4_0();
  for (int r = blockIdx.x * 16 + g; r < R; r += gridDim.x * 16) {
    float4 v = *reinterpret_cast<const float4*>(X + (size_t)r * 64 + dc);
    s.x += v.x; s.y += v.y; s.z += v.z; s.w += v.w;
    q.x = fmaf(v.x, v.x, q.x); q.y = fmaf(v.y, v.y, q.y);
    q.z = fmaf(v.z, v.z, q.z); q.w = fmaf(v.w, v.w, q.w);
  }
  *reinterpret_cast<float4*>(&red[0][g][dc]) = s;
  *reinterpret_cast<float4*>(&red[1][g][dc]) = q;
  __syncthreads();
  if (g == 0) {
    float4 ts = f4_0(), tq = f4_0();
#pragma unroll
    for (int gg = 0; gg < 16; ++gg) {
      float4 a = *reinterpret_cast<const float4*>(&red[0][gg][dc]);
      float4 b = *reinterpret_cast<const float4*>(&red[1][gg][dc]);
      ts.x += a.x; ts.y += a.y; ts.z += a.z; ts.w += a.w;
      tq.x += b.x; tq.y += b.y; tq.z += b.z; tq.w += b.w;
    }
    atomicAdd(&sums[dc], ts.x); atomicAdd(&sums[dc + 1], ts.y);
    atomicAdd(&sums[dc + 2], ts.z); atomicAdd(&sums[dc + 3], ts.w);
    atomicAdd(&sums[64 + dc], tq.x); atomicAdd(&sums[64 + dc + 1], tq.y);
    atomicAdd(&sums[64 + dc + 2], tq.z); atomicAdd(&sums[64 + dc + 3], tq.w);
  }
}

// ---------- fold BN stats into scale/shift ----------
__global__ void k_finalize(const float* __restrict__ sums, int R,
                           const float* __restrict__ gamma,
                           const float* __restrict__ beta,
                           float* __restrict__ coef) {
  int t = threadIdx.x;
  if (t < 64) {
    float mean = sums[t] / (float)R;
    float var = sums[64 + t] / (float)R - mean * mean;
    float sc = gamma[t] * rsqrtf(var + 1e-5f);
    coef[t] = sc;
    coef[64 + t] = beta[t] - mean * sc;
  }
}

// ---------- X += relu(scale*Y + shift) ----------
__global__ __launch_bounds__(256) void k_update(float* __restrict__ X,
                                                const float* __restrict__ Y,
                                                const float* __restrict__ coef, int R) {
  int idx = blockIdx.x * 256 + threadIdx.x;
  if (idx >= R * 16) return;
  int r = idx >> 4, dc = (idx & 15) << 2;
  float4 sc = *reinterpret_cast<const float4*>(coef + dc);
  float4 sh = *reinterpret_cast<const float4*>(coef + 64 + dc);
  size_t off = (size_t)r * 64 + dc;
  float4 y = *reinterpret_cast<const float4*>(Y + off);
  float4 x = *reinterpret_cast<const float4*>(X + off);
  x.x += fmaxf(fmaf(sc.x, y.x, sh.x), 0.f);
  x.y += fmaxf(fmaf(sc.y, y.y, sh.y), 0.f);
  x.z += fmaxf(fmaf(sc.z, y.z, sh.z), 0.f);
  x.w += fmaxf(fmaf(sc.w, y.w, sh.w), 0.f);
  *reinterpret_cast<float4*>(X + off) = x;
}

// ---------- decoder via MFMA ----------
// D[edge][n] = z @ W1, z = [h_src | h_dst | e] (192). W1^T staged in bf16 LDS.
__global__ __launch_bounds__(256) void k_decoder_mfma(const float* __restrict__ h,
                                                      const float* __restrict__ e,
                                                      const int* __restrict__ src,
                                                      const int* __restrict__ dst,
                                                      const float* __restrict__ W1,
                                                      const float* __restrict__ b1,
                                                      const float* __restrict__ W2,
                                                      const float* __restrict__ b2,
                                                      float* __restrict__ out, int E) {
  __shared__ unsigned short Wt[64 * 200];  // Wt[n][k], k=0..191, stride 200 (2-way banks)
  const int tid = threadIdx.x;
  for (int i = tid; i < 64 * 192; i += 256) {
    int n = i & 63, k = i >> 6;
    Wt[n * 200 + k] = f2bf(W1[k * 64 + n]);
  }
  __syncthreads();
  const int wid = tid >> 6, lane = tid & 63;
  const int col = lane & 15, g = lane >> 4;
  const int eb = (blockIdx.x * 4 + wid) * 16;
  int edge = eb + col;
  if (edge >= E) edge = E - 1;
  const int se = src[edge], de = dst[edge];
  const float* abase0 = h + (size_t)se * 64;
  const float* abase1 = h + (size_t)de * 64;
  const float* abase2 = e + (size_t)edge * 64;
  f32x4 acc[4] = {};
#pragma unroll
  for (int ks = 0; ks < 6; ++ks) {
    const float* ap = (ks < 2 ? abase0 : (ks < 4 ? abase1 : abase2)) + (ks & 1) * 32 + g * 8;
    float4 a0 = *reinterpret_cast<const float4*>(ap);
    float4 a1 = *reinterpret_cast<const float4*>(ap + 4);
    short8 af = pack_bf16x8(a0, a1);
#pragma unroll
    for (int nt = 0; nt < 4; ++nt) {
      const unsigned short* bp = &Wt[(nt * 16 + col) * 200 + ks * 32 + g * 8];
      uint2 lo = *reinterpret_cast<const uint2*>(bp);
      uint2 hi = *reinterpret_cast<const uint2*>(bp + 4);
      union { unsigned u[4]; short8 v; } bb;
      bb.u[0] = lo.x; bb.u[1] = lo.y; bb.u[2] = hi.x; bb.u[3] = hi.y;
      acc[nt] = __builtin_amdgcn_mfma_f32_16x16x32_bf16(af, bb.v, acc[nt], 0, 0, 0);
    }
  }
  // epilogue: p[m] = sum_n relu(acc + b1[n]) * W2[n]; lane n = nt*16+col
  float b1v[4], w2v[4];
#pragma unroll
  for (int nt = 0; nt < 4; ++nt) { b1v[nt] = b1[nt * 16 + col]; w2v[nt] = W2[nt * 16 + col]; }
  float pr[4];
#pragma unroll
  for (int r = 0; r < 4; ++r) {
    float s = 0.f;
#pragma unroll
    for (int nt = 0; nt < 4; ++nt)
      s = fmaf(fmaxf(acc[nt][r] + b1v[nt], 0.f), w2v[nt], s);
    pr[r] = s;
  }
#pragma unroll
  for (int off = 1; off <= 8; off <<= 1)
#pragma unroll
    for (int r = 0; r < 4; ++r)
      pr[r] += __shfl_xor(pr[r], off, 64);
  if (col == 0) {
    const float bb2 = b2[0];
#pragma unroll
    for (int r = 0; r < 4; ++r) {
      int m = eb + g * 4 + r;
      if (m < E) out[m] = pr[r] + bb2;
    }
  }
}

extern "C" void kernel_launch(void* const* d_in, const int* in_sizes, int n_in,
                              void* d_out, int out_size, void* d_ws, size_t ws_size,
                              hipStream_t stream) {
  const float* reads  = (const float*)d_in[0];
  const int*   src    = (const int*)d_in[1];
  const int*   dst    = (const int*)d_in[2];
  const float* sim    = (const float*)d_in[3];
  const float* olen   = (const float*)d_in[4];
  const float* conv_w = (const float*)d_in[5];
  const float* conv_b = (const float*)d_in[6];
  const float* We     = (const float*)d_in[7];
  const float* be     = (const float*)d_in[8];
  const float* A1     = (const float*)d_in[9];
  const float* A2     = (const float*)d_in[10];
  const float* A3     = (const float*)d_in[11];
  const float* bA1    = (const float*)d_in[12];
  const float* bA2    = (const float*)d_in[13];
  const float* bA3    = (const float*)d_in[14];
  const float* U      = (const float*)d_in[15];
  const float* V      = (const float*)d_in[16];
  const float* bU     = (const float*)d_in[17];
  const float* bV     = (const float*)d_in[18];
  const float* bnhg   = (const float*)d_in[19];
  const float* bnhb   = (const float*)d_in[20];
  const float* bneg   = (const float*)d_in[21];
  const float* bneb   = (const float*)d_in[22];
  const float* W1     = (const float*)d_in[23];
  const float* b1     = (const float*)d_in[24];
  const float* W2     = (const float*)d_in[25];
  const float* b2     = (const float*)d_in[26];

  const int N = in_sizes[0] / 512;
  const int E = in_sizes[1];

  float* p = (float*)d_ws;
  float* h    = p; p += (size_t)N * 64;
  float* e    = p; p += (size_t)E * 64;
  float* ehat = p; p += (size_t)E * 64;
  float* XA1  = p; p += (size_t)N * 64;
  float* XA2  = p; p += (size_t)N * 64;
  float* XV   = p; p += (size_t)N * 64;
  float* hhat = p; p += (size_t)N * 64;
  float* numb = p; p += (size_t)N * 64;
  float* denb = p; p += (size_t)N * 64;
  float* sums = p; p += 256;
  float* coef = p; p += 256;
  int* ip = (int*)p;
  int* cnt     = ip; ip += N;
  int* row_ptr = ip; ip += N + 1;
  int* nxt     = ip; ip += N;
  int* order   = ip; ip += E;
  float* out = (float*)d_out;

  // CSR of dst
  hipMemsetAsync(cnt, 0, sizeof(int) * N, stream);
  k_hist<<<(E + 255) / 256, 256, 0, stream>>>(dst, cnt, E);
  k_scan<<<1, 1024, 0, stream>>>(cnt, row_ptr, nxt, N, E);
  k_scatter<<<(E + 255) / 256, 256, 0, stream>>>(dst, nxt, order, E);

  k_conv_mfma<<<(N + 3) / 4, 256, 0, stream>>>(reads, conv_w, conv_b, h, N);
  k_edge_enc<<<(E * 16 + 255) / 256, 256, 0, stream>>>(sim, olen, We, be, e, E);

  const int eblocks = (E + 63) / 64;
  for (int l = 0; l < 4; ++l) {
    hipMemsetAsync(sums, 0, sizeof(float) * 256, stream);
    k_node_gemm<<<dim3((N + 255) / 256, 3), 256, 0, stream>>>(
        h, A1 + l * 4096, A2 + l * 4096, V + l * 4096,
        bA1 + l * 64, bA2 + l * 64, bV + l * 64, XA1, XA2, XV, N);
    k_edge_mfma<<<eblocks, 256, 0, stream>>>(
        e, src, dst, XA1, XA2, A3 + l * 4096, bA3 + l * 64, ehat, sums, E);
    k_finalize<<<1, 64, 0, stream>>>(sums, E, bneg + l * 64, bneb + l * 64, coef);
    k_aggregate_upd<<<(N * 16 + 255) / 256, 256, 0, stream>>>(
        row_ptr, order, src, ehat, XV, coef, e, numb, denb, N);
    k_hhat<<<(N + 255) / 256, 256, 0, stream>>>(
        h, U + l * 4096, bU + l * 64, numb, denb, hhat, N);
    k_stats<<<256, 256, 0, stream>>>(hhat, N, sums + 128);
    k_finalize<<<1, 64, 0, stream>>>(sums + 128, N, bnhg + l * 64, bnhb + l * 64, coef + 128);
    k_update<<<(N * 16 + 255) / 256, 256, 0, stream>>>(h, hhat, coef + 128, N);
  }

  k_decoder_mfma<<<eblocks, 256, 0, stream>>>(h, e, src, dst, W1, b1, W2, b2, out, E);
}

// Round 4
// 1520.852 us; speedup vs baseline: 1.8864x; 1.1874x over previous
//
#include <hip/hip_runtime.h>
#include <hip/hip_bf16.h>
#include <cstdint>
#include <cstddef>

#define DD 64

typedef __attribute__((ext_vector_type(8))) short short8;
typedef __attribute__((ext_vector_type(4))) float f32x4;

__device__ __forceinline__ float4 f4_0() { return make_float4(0.f, 0.f, 0.f, 0.f); }

__device__ __forceinline__ unsigned short f2bf(float f) {
  __hip_bfloat16 h = __float2bfloat16(f);
  return *reinterpret_cast<unsigned short*>(&h);
}

__device__ __forceinline__ short8 pack_bf16x8(float4 a, float4 b) {
  union { unsigned short us[8]; short8 v; } pk;
  pk.us[0] = f2bf(a.x); pk.us[1] = f2bf(a.y); pk.us[2] = f2bf(a.z); pk.us[3] = f2bf(a.w);
  pk.us[4] = f2bf(b.x); pk.us[5] = f2bf(b.y); pk.us[6] = f2bf(b.z); pk.us[7] = f2bf(b.w);
  return pk.v;
}

__device__ __forceinline__ short8 lds_frag(const unsigned short* p) {
  uint2 lo = *reinterpret_cast<const uint2*>(p);
  uint2 hi = *reinterpret_cast<const uint2*>(p + 4);
  union { unsigned u[4]; short8 v; } t;
  t.u[0] = lo.x; t.u[1] = lo.y; t.u[2] = hi.x; t.u[3] = hi.y;
  return t.v;
}

// ---------- row GEMM (fp32, node-side) ----------
__device__ __forceinline__ void row_gemm64(const float* __restrict__ row,
                                           const float* __restrict__ W,
                                           float acc[DD]) {
  for (int k4 = 0; k4 < DD; k4 += 4) {
    const float4 rv = *reinterpret_cast<const float4*>(row + k4);
    const float rvals[4] = {rv.x, rv.y, rv.z, rv.w};
#pragma unroll
    for (int kk = 0; kk < 4; ++kk) {
      const float v = rvals[kk];
      const float* wr = W + (k4 + kk) * DD;
#pragma unroll
      for (int d = 0; d < DD; ++d) acc[d] = fmaf(v, wr[d], acc[d]);
    }
  }
}

__device__ __forceinline__ void init_bias64(const float* __restrict__ b, float acc[DD]) {
#pragma unroll
  for (int d = 0; d < DD; ++d) acc[d] = b[d];
}

// ---------- CSR build ----------
__global__ __launch_bounds__(256) void k_hist(const int* __restrict__ dst,
                                              int* __restrict__ cnt, int E) {
  int j = blockIdx.x * 256 + threadIdx.x;
  if (j < E) atomicAdd(&cnt[dst[j]], 1);
}

__global__ __launch_bounds__(1024) void k_scan(const int* __restrict__ cnt,
                                               int* __restrict__ row_ptr,
                                               int* __restrict__ nxt, int N, int E) {
  __shared__ int wsum[16];
  __shared__ int carry_s;
  const int tid = threadIdx.x;
  const int wid = tid >> 6, lane = tid & 63;
  if (tid == 0) carry_s = 0;
  __syncthreads();
  const int nt = (N + 1023) / 1024;
  for (int b = 0; b < nt; ++b) {
    int i = b * 1024 + tid;
    int v = (i < N) ? cnt[i] : 0;
    int x = v;
#pragma unroll
    for (int off = 1; off < 64; off <<= 1) {
      int y = __shfl_up(x, off, 64);
      if (lane >= off) x += y;
    }
    if (lane == 63) wsum[wid] = x;
    __syncthreads();
    if (wid == 0 && lane < 16) {
      int wv = wsum[lane];
#pragma unroll
      for (int off = 1; off < 16; off <<= 1) {
        int y = __shfl_up(wv, off, 64);
        if (lane >= off) wv += y;
      }
      wsum[lane] = wv;
    }
    __syncthreads();
    int base = carry_s + (wid > 0 ? wsum[wid - 1] : 0);
    int excl = base + x - v;
    if (i < N) { row_ptr[i] = excl; nxt[i] = excl; }
    __syncthreads();
    if (tid == 0) carry_s += wsum[15];
    __syncthreads();
  }
  if (tid == 0) row_ptr[N] = E;
}

__global__ __launch_bounds__(256) void k_scatter(const int* __restrict__ dst,
                                                 int* __restrict__ nxt,
                                                 int* __restrict__ order, int E) {
  int j = blockIdx.x * 256 + threadIdx.x;
  if (j >= E) return;
  int pos = atomicAdd(&nxt[dst[j]], 1);
  order[pos] = j;
}

// ---------- conv1d + maxpool via bf16 MFMA ----------
__global__ __launch_bounds__(256) void k_conv_mfma(const float* __restrict__ reads,
                                                   const float* __restrict__ w,
                                                   const float* __restrict__ bias,
                                                   float* __restrict__ h, int N) {
  __shared__ unsigned short cp[4 * 4 * 4 * 144];  // [node][c][s][144]
  const int tid = threadIdx.x;
  const int nb = blockIdx.x * 4;
  for (int task = tid; task < 576; task += 256) {
    const int node = task / 144;
    const int rem = task % 144;
    const int c = rem / 36;
    const int u = rem % 36;
    const int gn = nb + node;
    float4 v0 = f4_0(), v1 = f4_0();
    if (gn < N) {
      const float* rp = reads + (size_t)gn * 512 + c * 128 + 4 * u;
      if (u <= 31) v0 = *reinterpret_cast<const float4*>(rp);
      if (u <= 30) v1 = *reinterpret_cast<const float4*>(rp + 4);
    }
    unsigned short us[8];
    us[0] = f2bf(v0.x); us[1] = f2bf(v0.y); us[2] = f2bf(v0.z); us[3] = f2bf(v0.w);
    us[4] = f2bf(v1.x); us[5] = f2bf(v1.y); us[6] = f2bf(v1.z); us[7] = f2bf(v1.w);
    const int base = ((node * 4 + c) * 4) * 144 + 4 * u;
#pragma unroll
    for (int s = 0; s < 4; ++s) {
      uint2 pk;
      pk.x = (unsigned)us[s] | ((unsigned)us[s + 1] << 16);
      pk.y = (unsigned)us[s + 2] | ((unsigned)us[s + 3] << 16);
      *reinterpret_cast<uint2*>(&cp[base + s * 144]) = pk;
    }
  }
  __syncthreads();
  const int wid = tid >> 6, lane = tid & 63;
  const int gn = nb + wid;
  if (gn >= N) return;
  const int col = lane & 15, grp = lane >> 4;
  short8 af[4][2];
#pragma unroll
  for (int mt = 0; mt < 4; ++mt)
#pragma unroll
    for (int ks = 0; ks < 2; ++ks) {
      const int d = col + 16 * mt;
      const int kb = ks * 32 + grp * 8;
      const float* wp = w + d * 64 + kb;
      float4 w0 = *reinterpret_cast<const float4*>(wp);
      float4 w1 = *reinterpret_cast<const float4*>(wp + 4);
      af[mt][ks] = pack_bf16x8(w0, w1);
    }
  float vmax[4][4];
#pragma unroll
  for (int mt = 0; mt < 4; ++mt)
#pragma unroll
    for (int r = 0; r < 4; ++r) vmax[mt][r] = -3.0e38f;
  const int s = col & 3;
  for (int ntile = 0; ntile < 8; ++ntile) {
    const int t = ntile * 16 + col;
    f32x4 acc[4] = {};
#pragma unroll
    for (int ks = 0; ks < 2; ++ks) {
      const int kbase = ks * 32 + grp * 8;
      const int c = kbase >> 4;
      const int kk0 = kbase & 15;
      const int q = (t - s) + kk0;
      const unsigned short* p = &cp[((wid * 4 + c) * 4 + s) * 144 + q];
      short8 bb = lds_frag(p);
#pragma unroll
      for (int mt = 0; mt < 4; ++mt)
        acc[mt] = __builtin_amdgcn_mfma_f32_16x16x32_bf16(af[mt][ks], bb, acc[mt], 0, 0, 0);
    }
    if (t < 113) {
#pragma unroll
      for (int mt = 0; mt < 4; ++mt)
#pragma unroll
        for (int r = 0; r < 4; ++r) vmax[mt][r] = fmaxf(vmax[mt][r], acc[mt][r]);
    }
  }
#pragma unroll
  for (int off = 8; off >= 1; off >>= 1)
#pragma unroll
    for (int mt = 0; mt < 4; ++mt)
#pragma unroll
      for (int r = 0; r < 4; ++r)
        vmax[mt][r] = fmaxf(vmax[mt][r], __shfl_xor(vmax[mt][r], off, 64));
  if (col == 0) {
#pragma unroll
    for (int mt = 0; mt < 4; ++mt)
#pragma unroll
      for (int r = 0; r < 4; ++r) {
        const int d = mt * 16 + grp * 4 + r;
        h[(size_t)gn * 64 + d] = vmax[mt][r] + bias[d];
      }
  }
}

// ---------- edge encoder ----------
__global__ __launch_bounds__(256) void k_edge_enc(const float* __restrict__ sim,
                                                  const float* __restrict__ len,
                                                  const float* __restrict__ We,
                                                  const float* __restrict__ be,
                                                  float* __restrict__ e, int E) {
  int idx = blockIdx.x * 256 + threadIdx.x;
  if (idx >= E * 16) return;
  int j = idx >> 4, dc = (idx & 15) << 2;
  float s = sim[j], L = len[j];
  float4 w0 = *reinterpret_cast<const float4*>(We + dc);
  float4 w1 = *reinterpret_cast<const float4*>(We + 64 + dc);
  float4 b  = *reinterpret_cast<const float4*>(be + dc);
  float4 o;
  o.x = fmaf(s, w0.x, fmaf(L, w1.x, b.x));
  o.y = fmaf(s, w0.y, fmaf(L, w1.y, b.y));
  o.z = fmaf(s, w0.z, fmaf(L, w1.z, b.z));
  o.w = fmaf(s, w0.w, fmaf(L, w1.w, b.w));
  *reinterpret_cast<float4*>(e + (size_t)j * 64 + dc) = o;
}

// ---------- node GEMMs (fp32) ----------
__global__ __launch_bounds__(256) void k_node_gemm(const float* __restrict__ h,
                                                   const float* __restrict__ Wa,
                                                   const float* __restrict__ Wb,
                                                   const float* __restrict__ Wc,
                                                   const float* __restrict__ ba,
                                                   const float* __restrict__ bb,
                                                   const float* __restrict__ bc,
                                                   float* __restrict__ Xa,
                                                   float* __restrict__ Xb,
                                                   float* __restrict__ Xc, int N) {
  const float* W; const float* bi; float* X;
  if (blockIdx.y == 0)      { W = Wa; bi = ba; X = Xa; }
  else if (blockIdx.y == 1) { W = Wb; bi = bb; X = Xb; }
  else                      { W = Wc; bi = bc; X = Xc; }
  int n = blockIdx.x * 256 + threadIdx.x;
  if (n >= N) return;
  float acc[DD];
  init_bias64(bi, acc);
  row_gemm64(h + (size_t)n * 64, W, acc);
#pragma unroll
  for (int dc = 0; dc < DD; dc += 4) {
    float4 v = make_float4(acc[dc], acc[dc + 1], acc[dc + 2], acc[dc + 3]);
    *reinterpret_cast<float4*>(X + (size_t)n * 64 + dc) = v;
  }
}

// ---------- persistent edge MFMA: A3^T frags in registers, reg-accumulated BN stats ----------
__global__ __launch_bounds__(256) void k_edge_mfma(const float* __restrict__ e,
                                                   const int* __restrict__ src,
                                                   const int* __restrict__ dst,
                                                   const float* __restrict__ XA1,
                                                   const float* __restrict__ XA2,
                                                   const float* __restrict__ A3,
                                                   const float* __restrict__ bA3,
                                                   float* __restrict__ ehat,
                                                   float* __restrict__ sums, int E) {
  __shared__ unsigned short At[64 * 72];
  __shared__ float s_sums[128];
  const int tid = threadIdx.x;
  if (tid < 128) s_sums[tid] = 0.f;
  for (int i = tid; i < 4096; i += 256) {
    int n = i & 63, k = i >> 6;
    At[n * 72 + k] = f2bf(A3[k * 64 + n]);
  }
  __syncthreads();
  const int wid = tid >> 6, lane = tid & 63;
  const int col = lane & 15, g = lane >> 4;
  // hoist A-fragments to registers once; LDS untouched afterwards
  short8 aa[4][2];
#pragma unroll
  for (int mt = 0; mt < 4; ++mt)
#pragma unroll
    for (int ks = 0; ks < 2; ++ks)
      aa[mt][ks] = lds_frag(&At[(mt * 16 + col) * 72 + ks * 32 + g * 8]);
  float4 ba[4];
#pragma unroll
  for (int mt = 0; mt < 4; ++mt)
    ba[mt] = *reinterpret_cast<const float4*>(bA3 + mt * 16 + g * 4);
  float statS[16], statQ[16];
#pragma unroll
  for (int i = 0; i < 16; ++i) { statS[i] = 0.f; statQ[i] = 0.f; }
  const int ntiles = (E + 15) / 16;
  for (int tw = blockIdx.x * 4 + wid; tw < ntiles; tw += gridDim.x * 4) {
    int edge = tw * 16 + col;
    const bool valid = edge < E;
    if (!valid) edge = E - 1;
    const int se = src[edge], de = dst[edge];
    f32x4 acc[4] = {};
#pragma unroll
    for (int ks = 0; ks < 2; ++ks) {
      const float* bp = e + (size_t)edge * 64 + ks * 32 + g * 8;
      float4 b0 = *reinterpret_cast<const float4*>(bp);
      float4 b1v = *reinterpret_cast<const float4*>(bp + 4);
      short8 bfr = pack_bf16x8(b0, b1v);
#pragma unroll
      for (int mt = 0; mt < 4; ++mt)
        acc[mt] = __builtin_amdgcn_mfma_f32_16x16x32_bf16(aa[mt][ks], bfr, acc[mt], 0, 0, 0);
    }
#pragma unroll
    for (int mt = 0; mt < 4; ++mt) {
      const int chb = mt * 16 + g * 4;
      float4 x1 = *reinterpret_cast<const float4*>(XA1 + (size_t)se * 64 + chb);
      float4 x2 = *reinterpret_cast<const float4*>(XA2 + (size_t)de * 64 + chb);
      float o0 = acc[mt][0] + x1.x + x2.x + ba[mt].x;
      float o1 = acc[mt][1] + x1.y + x2.y + ba[mt].y;
      float o2 = acc[mt][2] + x1.z + x2.z + ba[mt].z;
      float o3 = acc[mt][3] + x1.w + x2.w + ba[mt].w;
      if (valid) {
        *reinterpret_cast<float4*>(ehat + (size_t)edge * 64 + chb) =
            make_float4(o0, o1, o2, o3);
        statS[mt * 4 + 0] += o0; statQ[mt * 4 + 0] = fmaf(o0, o0, statQ[mt * 4 + 0]);
        statS[mt * 4 + 1] += o1; statQ[mt * 4 + 1] = fmaf(o1, o1, statQ[mt * 4 + 1]);
        statS[mt * 4 + 2] += o2; statQ[mt * 4 + 2] = fmaf(o2, o2, statQ[mt * 4 + 2]);
        statS[mt * 4 + 3] += o3; statQ[mt * 4 + 3] = fmaf(o3, o3, statQ[mt * 4 + 3]);
      }
    }
  }
  // one reduction at kernel end: sum across the 16 col-lanes of each g-group
#pragma unroll
  for (int off = 1; off <= 8; off <<= 1)
#pragma unroll
    for (int i = 0; i < 16; ++i) {
      statS[i] += __shfl_xor(statS[i], off, 64);
      statQ[i] += __shfl_xor(statQ[i], off, 64);
    }
  if (col == 0) {
#pragma unroll
    for (int mt = 0; mt < 4; ++mt)
#pragma unroll
      for (int c = 0; c < 4; ++c) {
        const int ch = mt * 16 + g * 4 + c;
        atomicAdd(&s_sums[ch], statS[mt * 4 + c]);
        atomicAdd(&s_sums[64 + ch], statQ[mt * 4 + c]);
      }
  }
  __syncthreads();
  if (tid < 128) atomicAdd(&sums[tid], s_sums[tid]);
}

// ---------- fused aggregation + e-update ----------
__global__ __launch_bounds__(256) void k_aggregate_upd(const int* __restrict__ row_ptr,
                                                       const int* __restrict__ order,
                                                       const int* __restrict__ src,
                                                       const float* __restrict__ ehat,
                                                       const float* __restrict__ XV,
                                                       const float* __restrict__ coef_e,
                                                       float* __restrict__ e,
                                                       float* __restrict__ num,
                                                       float* __restrict__ den, int N) {
  int idx = blockIdx.x * 256 + threadIdx.x;
  if (idx >= N * 16) return;
  int n = idx >> 4, dc = (idx & 15) << 2;
  int beg = row_ptr[n], end = row_ptr[n + 1];
  float4 sc = *reinterpret_cast<const float4*>(coef_e + dc);
  float4 sh = *reinterpret_cast<const float4*>(coef_e + 64 + dc);
  float4 nm = f4_0(), dn = f4_0();
  for (int i = beg; i < end; ++i) {
    int eid = order[i];
    int sj = src[eid];
    size_t eoff = (size_t)eid * 64 + dc;
    float4 eh = *reinterpret_cast<const float4*>(ehat + eoff);
    float4 vv = *reinterpret_cast<const float4*>(XV + (size_t)sj * 64 + dc);
    float4 sg;
    sg.x = 1.f / (1.f + __expf(-eh.x));
    sg.y = 1.f / (1.f + __expf(-eh.y));
    sg.z = 1.f / (1.f + __expf(-eh.z));
    sg.w = 1.f / (1.f + __expf(-eh.w));
    dn.x += sg.x; dn.y += sg.y; dn.z += sg.z; dn.w += sg.w;
    nm.x = fmaf(sg.x, vv.x, nm.x); nm.y = fmaf(sg.y, vv.y, nm.y);
    nm.z = fmaf(sg.z, vv.z, nm.z); nm.w = fmaf(sg.w, vv.w, nm.w);
    float4 ev = *reinterpret_cast<const float4*>(e + eoff);
    ev.x += fmaxf(fmaf(sc.x, eh.x, sh.x), 0.f);
    ev.y += fmaxf(fmaf(sc.y, eh.y, sh.y), 0.f);
    ev.z += fmaxf(fmaf(sc.z, eh.z, sh.z), 0.f);
    ev.w += fmaxf(fmaf(sc.w, eh.w, sh.w), 0.f);
    *reinterpret_cast<float4*>(e + eoff) = ev;
  }
  *reinterpret_cast<float4*>(num + (size_t)n * 64 + dc) = nm;
  *reinterpret_cast<float4*>(den + (size_t)n * 64 + dc) = dn;
}

// ---------- h_hat (fp32) ----------
__global__ __launch_bounds__(256) void k_hhat(const float* __restrict__ h,
                                              const float* __restrict__ Uw,
                                              const float* __restrict__ bU,
                                              const float* __restrict__ num,
                                              const float* __restrict__ den,
                                              float* __restrict__ hhat, int N) {
  int n = blockIdx.x * 256 + threadIdx.x;
  if (n >= N) return;
  float acc[DD];
  init_bias64(bU, acc);
  row_gemm64(h + (size_t)n * 64, Uw, acc);
#pragma unroll
  for (int dc = 0; dc < DD; dc += 4) {
    float4 nm = *reinterpret_cast<const float4*>(num + (size_t)n * 64 + dc);
    float4 dn = *reinterpret_cast<const float4*>(den + (size_t)n * 64 + dc);
    float4 o = make_float4(acc[dc] + nm.x / (dn.x + 1e-6f),
                           acc[dc + 1] + nm.y / (dn.y + 1e-6f),
                           acc[dc + 2] + nm.z / (dn.z + 1e-6f),
                           acc[dc + 3] + nm.w / (dn.w + 1e-6f));
    *reinterpret_cast<float4*>(hhat + (size_t)n * 64 + dc) = o;
  }
}

// ---------- per-channel sum & sumsq (hhat only) ----------
__global__ __launch_bounds__(256) void k_stats(const float* __restrict__ X, int R,
                                               float* __restrict__ sums) {
  __shared__ float red[2][16][64];
  int tid = threadIdx.x;
  int g = tid >> 4, dc = (tid & 15) << 2;
  float4 s = f4_0(), q = f4_0();
  for (int r = blockIdx.x * 16 + g; r < R; r += gridDim.x * 16) {
    float4 v = *reinterpret_cast<const float4*>(X + (size_t)r * 64 + dc);
    s.x += v.x; s.y += v.y; s.z += v.z; s.w += v.w;
    q.x = fmaf(v.x, v.x, q.x); q.y = fmaf(v.y, v.y, q.y);
    q.z = fmaf(v.z, v.z, q.z); q.w = fmaf(v.w, v.w, q.w);
  }
  *reinterpret_cast<float4*>(&red[0][g][dc]) = s;
  *reinterpret_cast<float4*>(&red[1][g][dc]) = q;
  __syncthreads();
  if (g == 0) {
    float4 ts = f4_0(), tq = f4_0();
#pragma unroll
    for (int gg = 0; gg < 16; ++gg) {
      float4 a = *reinterpret_cast<const float4*>(&red[0][gg][dc]);
      float4 b = *reinterpret_cast<const float4*>(&red[1][gg][dc]);
      ts.x += a.x; ts.y += a.y; ts.z += a.z; ts.w += a.w;
      tq.x += b.x; tq.y += b.y; tq.z += b.z; tq.w += b.w;
    }
    atomicAdd(&sums[dc], ts.x); atomicAdd(&sums[dc + 1], ts.y);
    atomicAdd(&sums[dc + 2], ts.z); atomicAdd(&sums[dc + 3], ts.w);
    atomicAdd(&sums[64 + dc], tq.x); atomicAdd(&sums[64 + dc + 1], tq.y);
    atomicAdd(&sums[64 + dc + 2], tq.z); atomicAdd(&sums[64 + dc + 3], tq.w);
  }
}

// ---------- fold BN stats into scale/shift ----------
__global__ void k_finalize(const float* __restrict__ sums, int R,
                           const float* __restrict__ gamma,
                           const float* __restrict__ beta,
                           float* __restrict__ coef) {
  int t = threadIdx.x;
  if (t < 64) {
    float mean = sums[t] / (float)R;
    float var = sums[64 + t] / (float)R - mean * mean;
    float sc = gamma[t] * rsqrtf(var + 1e-5f);
    coef[t] = sc;
    coef[64 + t] = beta[t] - mean * sc;
  }
}

// ---------- X += relu(scale*Y + shift) ----------
__global__ __launch_bounds__(256) void k_update(float* __restrict__ X,
                                                const float* __restrict__ Y,
                                                const float* __restrict__ coef, int R) {
  int idx = blockIdx.x * 256 + threadIdx.x;
  if (idx >= R * 16) return;
  int r = idx >> 4, dc = (idx & 15) << 2;
  float4 sc = *reinterpret_cast<const float4*>(coef + dc);
  float4 sh = *reinterpret_cast<const float4*>(coef + 64 + dc);
  size_t off = (size_t)r * 64 + dc;
  float4 y = *reinterpret_cast<const float4*>(Y + off);
  float4 x = *reinterpret_cast<const float4*>(X + off);
  x.x += fmaxf(fmaf(sc.x, y.x, sh.x), 0.f);
  x.y += fmaxf(fmaf(sc.y, y.y, sh.y), 0.f);
  x.z += fmaxf(fmaf(sc.z, y.z, sh.z), 0.f);
  x.w += fmaxf(fmaf(sc.w, y.w, sh.w), 0.f);
  *reinterpret_cast<float4*>(X + off) = x;
}

// ---------- persistent decoder MFMA ----------
__global__ __launch_bounds__(256) void k_decoder_mfma(const float* __restrict__ h,
                                                      const float* __restrict__ e,
                                                      const int* __restrict__ src,
                                                      const int* __restrict__ dst,
                                                      const float* __restrict__ W1,
                                                      const float* __restrict__ b1,
                                                      const float* __restrict__ W2,
                                                      const float* __restrict__ b2,
                                                      float* __restrict__ out, int E) {
  __shared__ unsigned short Wt[64 * 200];  // Wt[n][k], stride 200 (2-way banks = free)
  const int tid = threadIdx.x;
  for (int i = tid; i < 64 * 192; i += 256) {
    int n = i & 63, k = i >> 6;
    Wt[n * 200 + k] = f2bf(W1[k * 64 + n]);
  }
  __syncthreads();
  const int wid = tid >> 6, lane = tid & 63;
  const int col = lane & 15, g = lane >> 4;
  float b1v[4], w2v[4];
#pragma unroll
  for (int nt = 0; nt < 4; ++nt) { b1v[nt] = b1[nt * 16 + col]; w2v[nt] = W2[nt * 16 + col]; }
  const float bb2 = b2[0];
  const int ntiles = (E + 15) / 16;
  for (int tw = blockIdx.x * 4 + wid; tw < ntiles; tw += gridDim.x * 4) {
    const int eb = tw * 16;
    int edge = eb + col;
    if (edge >= E) edge = E - 1;
    const int se = src[edge], de = dst[edge];
    const float* abase0 = h + (size_t)se * 64;
    const float* abase1 = h + (size_t)de * 64;
    const float* abase2 = e + (size_t)edge * 64;
    f32x4 acc[4] = {};
#pragma unroll
    for (int ks = 0; ks < 6; ++ks) {
      const float* ap = (ks < 2 ? abase0 : (ks < 4 ? abase1 : abase2)) + (ks & 1) * 32 + g * 8;
      float4 a0 = *reinterpret_cast<const float4*>(ap);
      float4 a1 = *reinterpret_cast<const float4*>(ap + 4);
      short8 af = pack_bf16x8(a0, a1);
#pragma unroll
      for (int nt = 0; nt < 4; ++nt) {
        short8 bb = lds_frag(&Wt[(nt * 16 + col) * 200 + ks * 32 + g * 8]);
        acc[nt] = __builtin_amdgcn_mfma_f32_16x16x32_bf16(af, bb, acc[nt], 0, 0, 0);
      }
    }
    float pr[4];
#pragma unroll
    for (int r = 0; r < 4; ++r) {
      float s = 0.f;
#pragma unroll
      for (int nt = 0; nt < 4; ++nt)
        s = fmaf(fmaxf(acc[nt][r] + b1v[nt], 0.f), w2v[nt], s);
      pr[r] = s;
    }
#pragma unroll
    for (int off = 1; off <= 8; off <<= 1)
#pragma unroll
      for (int r = 0; r < 4; ++r)
        pr[r] += __shfl_xor(pr[r], off, 64);
    if (col == 0) {
#pragma unroll
      for (int r = 0; r < 4; ++r) {
        int m = eb + g * 4 + r;
        if (m < E) out[m] = pr[r] + bb2;
      }
    }
  }
}

extern "C" void kernel_launch(void* const* d_in, const int* in_sizes, int n_in,
                              void* d_out, int out_size, void* d_ws, size_t ws_size,
                              hipStream_t stream) {
  const float* reads  = (const float*)d_in[0];
  const int*   src    = (const int*)d_in[1];
  const int*   dst    = (const int*)d_in[2];
  const float* sim    = (const float*)d_in[3];
  const float* olen   = (const float*)d_in[4];
  const float* conv_w = (const float*)d_in[5];
  const float* conv_b = (const float*)d_in[6];
  const float* We     = (const float*)d_in[7];
  const float* be     = (const float*)d_in[8];
  const float* A1     = (const float*)d_in[9];
  const float* A2     = (const float*)d_in[10];
  const float* A3     = (const float*)d_in[11];
  const float* bA1    = (const float*)d_in[12];
  const float* bA2    = (const float*)d_in[13];
  const float* bA3    = (const float*)d_in[14];
  const float* U      = (const float*)d_in[15];
  const float* V      = (const float*)d_in[16];
  const float* bU     = (const float*)d_in[17];
  const float* bV     = (const float*)d_in[18];
  const float* bnhg   = (const float*)d_in[19];
  const float* bnhb   = (const float*)d_in[20];
  const float* bneg   = (const float*)d_in[21];
  const float* bneb   = (const float*)d_in[22];
  const float* W1     = (const float*)d_in[23];
  const float* b1     = (const float*)d_in[24];
  const float* W2     = (const float*)d_in[25];
  const float* b2     = (const float*)d_in[26];

  const int N = in_sizes[0] / 512;
  const int E = in_sizes[1];

  float* p = (float*)d_ws;
  float* h    = p; p += (size_t)N * 64;
  float* e    = p; p += (size_t)E * 64;
  float* ehat = p; p += (size_t)E * 64;
  float* XA1  = p; p += (size_t)N * 64;
  float* XA2  = p; p += (size_t)N * 64;
  float* XV   = p; p += (size_t)N * 64;
  float* hhat = p; p += (size_t)N * 64;
  float* numb = p; p += (size_t)N * 64;
  float* denb = p; p += (size_t)N * 64;
  float* sums = p; p += 256;
  float* coef = p; p += 256;
  int* ip = (int*)p;
  int* cnt     = ip; ip += N;
  int* row_ptr = ip; ip += N + 1;
  int* nxt     = ip; ip += N;
  int* order   = ip; ip += E;
  float* out = (float*)d_out;

  // CSR of dst
  hipMemsetAsync(cnt, 0, sizeof(int) * N, stream);
  k_hist<<<(E + 255) / 256, 256, 0, stream>>>(dst, cnt, E);
  k_scan<<<1, 1024, 0, stream>>>(cnt, row_ptr, nxt, N, E);
  k_scatter<<<(E + 255) / 256, 256, 0, stream>>>(dst, nxt, order, E);

  k_conv_mfma<<<(N + 3) / 4, 256, 0, stream>>>(reads, conv_w, conv_b, h, N);
  k_edge_enc<<<(E * 16 + 255) / 256, 256, 0, stream>>>(sim, olen, We, be, e, E);

  const int PBLK = 1024;  // persistent-ish grid: ~6 tiles/wave, staging amortized
  for (int l = 0; l < 4; ++l) {
    hipMemsetAsync(sums, 0, sizeof(float) * 256, stream);
    k_node_gemm<<<dim3((N + 255) / 256, 3), 256, 0, stream>>>(
        h, A1 + l * 4096, A2 + l * 4096, V + l * 4096,
        bA1 + l * 64, bA2 + l * 64, bV + l * 64, XA1, XA2, XV, N);
    k_edge_mfma<<<PBLK, 256, 0, stream>>>(
        e, src, dst, XA1, XA2, A3 + l * 4096, bA3 + l * 64, ehat, sums, E);
    k_finalize<<<1, 64, 0, stream>>>(sums, E, bneg + l * 64, bneb + l * 64, coef);
    k_aggregate_upd<<<(N * 16 + 255) / 256, 256, 0, stream>>>(
        row_ptr, order, src, ehat, XV, coef, e, numb, denb, N);
    k_hhat<<<(N + 255) / 256, 256, 0, stream>>>(
        h, U + l * 4096, bU + l * 64, numb, denb, hhat, N);
    k_stats<<<256, 256, 0, stream>>>(hhat, N, sums + 128);
    k_finalize<<<1, 64, 0, stream>>>(sums + 128, N, bnhg + l * 64, bnhb + l * 64, coef + 128);
    k_update<<<(N * 16 + 255) / 256, 256, 0, stream>>>(h, hhat, coef + 128, N);
  }

  k_decoder_mfma<<<PBLK, 256, 0, stream>>>(h, e, src, dst, W1, b1, W2, b2, out, E);
}